// Round 15
// baseline (339.989 us; speedup 1.0000x reference)
//
#include <hip/hip_runtime.h>
#include <hip/hip_bf16.h>
#include <cstdint>

#define HIDDEN 384
#define NSUPER 2048
#define FRAGS (12*24*64)
#define WBLK  (FRAGS*8)             // shorts per repacked 384x384 block = 147456

typedef __attribute__((ext_vector_type(8))) short bf16x8;
typedef __attribute__((ext_vector_type(4))) float f32x4;

// branchless RNE f32->bf16 (finite values only)
__device__ inline unsigned short f2bf(float f) {
    unsigned int u = __float_as_uint(f);
    return (unsigned short)((u + 0x7fffu + ((u >> 16) & 1u)) >> 16);
}
__device__ inline bf16x8 pack8(const float* v) {
    union { bf16x8 v8; unsigned short u[8]; } u;
    #pragma unroll
    for (int i = 0; i < 8; ++i) u.u[i] = f2bf(v[i]);
    return u.v8;
}
// tanh-form gelu via sigmoid: ~9 VALU ops
__device__ inline float gelu(float y) {
    const float y2 = y * y;
    const float m  = __expf(y * fmaf(-0.0713548163f, y2, -1.5957691216f));
    return y * (1.0f / (1.0f + m));
}

// ---- K1: weight repacks + mask detect + supernode embeds ----
__global__ __launch_bounds__(256)
void prep(const float* __restrict__ W1, const float* __restrict__ W2,
          const float* __restrict__ Wp, const unsigned int* __restrict__ mask,
          const float* __restrict__ pos, const float* __restrict__ feat,
          const int* __restrict__ sn_idx,
          const float* __restrict__ W_in, const float* __restrict__ b_in,
          unsigned short* __restrict__ w1sf, unsigned short* __restrict__ w1df,
          unsigned short* __restrict__ w2f,  unsigned short* __restrict__ wpf,
          unsigned short* __restrict__ snxb, int* __restrict__ flag) {
    const int b = blockIdx.x;
    const int t = threadIdx.x;
    if (b == 360) {
        __shared__ int s;
        if (t == 0) s = 0;
        __syncthreads();
        int bad = 0;
        for (int i = t; i < 16384; i += 256)
            if (mask[i] > 1u) bad = 1;
        if (bad) s = 1;
        __syncthreads();
        if (t == 0) *flag = s;   // 1 => uint8, 0 => int32
        return;
    }
    if (b > 360) {    // supernode embeds -> snxb
        __shared__ float W4[HIDDEN][4];
        __shared__ float P6[64][7];
        const int eb = b - 361;
        if (t < 64) {
            const int pi = sn_idx[eb*64 + t];
            P6[t][0]=pos[pi*3];  P6[t][1]=pos[pi*3+1];  P6[t][2]=pos[pi*3+2];
            P6[t][3]=feat[pi*3]; P6[t][4]=feat[pi*3+1]; P6[t][5]=feat[pi*3+2];
        }
        for (int d = t; d < HIDDEN; d += 256) {
            W4[d][0]=W_in[d]; W4[d][1]=W_in[HIDDEN+d];
            W4[d][2]=W_in[2*HIDDEN+d]; W4[d][3]=b_in[d];
        }
        __syncthreads();
        const int er = t >> 2, seg = t & 3;
        float frA[8], frB[8];
        #pragma unroll
        for (int i = 0; i < 8; ++i) {
            frA[i] = exp2f(-(float)(seg*8 + i)      * 0.2076205059304601f);
            frB[i] = exp2f(-(float)(32 + seg*8 + i) * 0.2076205059304601f);
        }
        const float f0 = P6[er][3], f1 = P6[er][4], f2 = P6[er][5];
        #pragma unroll
        for (int cc = 0; cc < 3; ++cc) {
            const float pc = P6[er][cc];
            float sL[8], sH[8], cL[8], cH[8];
            #pragma unroll
            for (int i = 0; i < 8; ++i) {
                const float aL = pc*frA[i], aH = pc*frB[i];
                sL[i]=__sinf(aL); sH[i]=__sinf(aH); cL[i]=__cosf(aL); cH[i]=__cosf(aH);
            }
            #pragma unroll
            for (int q = 0; q < 4; ++q) {
                const float* bb = (q==0)?sL:(q==1)?sH:(q==2)?cL:cH;
                const int blk = cc*4 + q;
                float v[8];
                #pragma unroll
                for (int i = 0; i < 8; ++i) {
                    const int dim = blk*32 + seg*8 + i;
                    const float4 wv = *(const float4*)W4[dim];
                    v[i] = fmaf(f0, wv.x, fmaf(f1, wv.y, fmaf(f2, wv.z, bb[i] + wv.w)));
                }
                *(bf16x8*)&snxb[(size_t)(eb*64 + er)*HIDDEN + blk*32 + seg*8] = pack8(v);
            }
        }
        return;
    }
    const int grp = b / 72, sub = b % 72;
    const float* W; unsigned short* out;
    switch (grp) {
        case 0: W = W1;              out = w1sf; break;
        case 1: W = W1 + 384*HIDDEN; out = w1df; break;
        case 2: W = W2;              out = w2f;  break;
        case 3: W = Wp;              out = wpf;  break;
        default:W = Wp + 384*HIDDEN; out = wpf + WBLK; break;
    }
    const int idx = sub * 256 + t;
    const int l   = idx & 63;
    const int frag= idx >> 6;
    const int nt  = frag % 24;
    const int kt  = frag / 24;
    const int col = nt * 16 + (l & 15);
    const int k0  = kt * 32 + (l >> 4) * 8;
    unsigned int pk[4];
    #pragma unroll
    for (int j = 0; j < 4; ++j) {
        unsigned int lo = f2bf(W[(size_t)(k0 + 2*j)     * HIDDEN + col]);
        unsigned int hi = f2bf(W[(size_t)(k0 + 2*j + 1) * HIDDEN + col]);
        pk[j] = lo | (hi << 16);
    }
    *reinterpret_cast<uint4*>(&out[(size_t)idx * 8]) =
        *reinterpret_cast<const uint4*>(pk);
}

// ---- K2: dstv = snxb @ W1dst + b1 ----
__global__ __launch_bounds__(256)
void k_dstv(const unsigned short* __restrict__ snxb,
            const unsigned short* __restrict__ w1df,
            const float* __restrict__ b1, float* __restrict__ dstv) {
    const int rg = blockIdx.x >> 2, cq = blockIdx.x & 3;
    const int t = threadIdx.x, w = t>>6, l = t&63, lg = l>>4, l15 = l&15;
    const int wgm = w>>1, wgn = w&1;
    const int r0 = rg*64 + wgm*32;
    const int ntb = cq*6 + wgn*3;
    f32x4 acc[2][3];
    #pragma unroll
    for (int mt=0; mt<2; ++mt)
        #pragma unroll
        for (int nt=0; nt<3; ++nt) acc[mt][nt] = (f32x4){0.f,0.f,0.f,0.f};
    #pragma unroll 2
    for (int kt = 0; kt < 12; ++kt) {
        bf16x8 a[2], bfr[3];
        const unsigned short* bpp = &w1df[((size_t)(kt*24 + ntb)*64 + l)*8];
        #pragma unroll
        for (int nt=0; nt<3; ++nt) bfr[nt] = *(const bf16x8*)(bpp + (size_t)nt*512);
        #pragma unroll
        for (int mt=0; mt<2; ++mt)
            a[mt] = *(const bf16x8*)&snxb[(size_t)(r0 + mt*16 + l15)*HIDDEN + kt*32 + lg*8];
        #pragma unroll
        for (int mt=0; mt<2; ++mt)
            #pragma unroll
            for (int nt=0; nt<3; ++nt)
                acc[mt][nt] = __builtin_amdgcn_mfma_f32_16x16x32_bf16(a[mt], bfr[nt], acc[mt][nt], 0,0,0);
    }
    #pragma unroll
    for (int mt=0; mt<2; ++mt)
        #pragma unroll
        for (int nt=0; nt<3; ++nt) {
            const int col = cq*96 + wgn*48 + nt*16 + l15;
            #pragma unroll
            for (int r=0; r<4; ++r) {
                const int row = r0 + mt*16 + lg*4 + r;
                dstv[(size_t)row*HIDDEN + col] = acc[mt][nt][r] + b1[col];
            }
        }
}

// ---- shared MLP body for production + ablations (rule #8 template probe) ----
template<int REPS, bool EMB_ON, bool GEMM_ON>
__device__ __forceinline__ void mlp_body(
    const float* __restrict__ pos, const float* __restrict__ feat,
    const int* __restrict__ nbr_idx, const void* __restrict__ mask_raw,
    const int* __restrict__ mask_fmt,
    const float* __restrict__ W_in, const float* __restrict__ b_in,
    const float* __restrict__ dstv,
    const unsigned short* __restrict__ W1sf,
    unsigned short* __restrict__ aggpre, float* __restrict__ cntf)
{
    __shared__ unsigned short G[8*12*64*8];   // 98304 B frag-major
    __shared__ float4 WINT[HIDDEN];
    __shared__ float PF[128][7];
    __shared__ float CNT[4];

    const int t  = threadIdx.x;
    const int bm = blockIdx.x;
    const int l = t & 63, w = t >> 6;
    const int mg = w >> 2, ng = w & 3;
    const int lg = l >> 4, l15 = l & 15;

    float dvreg[2][6];
    #pragma unroll
    for (int sl = 0; sl < 2; ++sl)
        #pragma unroll
        for (int nt = 0; nt < 6; ++nt)
            dvreg[sl][nt] = dstv[(size_t)(bm*4 + mg*2 + sl)*HIDDEN + ng*96 + nt*16 + l15];

    if (t < 128) {
        const int e  = bm*128 + t;
        const int pi = nbr_idx[e];
        PF[t][0]=pos[pi*3];  PF[t][1]=pos[pi*3+1];  PF[t][2]=pos[pi*3+2];
        PF[t][3]=feat[pi*3]; PF[t][4]=feat[pi*3+1]; PF[t][5]=feat[pi*3+2];
        const int fmt = *mask_fmt;
        const int mv  = fmt ? (int)((const unsigned char*)mask_raw)[e]
                            : ((const int*)mask_raw)[e];
        PF[t][6] = mv ? 1.0f : 0.0f;
    }
    if (t >= 128 && t < 128 + HIDDEN) {
        const int d = t - 128;
        WINT[d] = (float4){W_in[d], W_in[HIDDEN+d], W_in[2*HIDDEN+d], b_in[d]};
    }
    __syncthreads();
    if (t < 4) {
        float c = 0.f;
        for (int s = 0; s < 32; ++s) c += PF[t*32+s][6];
        CNT[t] = c;
    }

    const int er = t >> 2, seg = t & 3;
    float frA[8], frB[8];
    #pragma unroll
    for (int i = 0; i < 8; ++i) {
        frA[i] = exp2f(-(float)(seg*8 + i)      * 0.2076205059304601f);
        frB[i] = exp2f(-(float)(32 + seg*8 + i) * 0.2076205059304601f);
    }
    const int slotbase = (er>>4)*12*64 + seg*16 + (er&15);

    #pragma unroll 1
    for (int rep = 0; rep < REPS; ++rep) {
        const float jit = (float)rep * 1e-30f;   // defeats LICM; rounds away

        // ---- embed phase ----
        if constexpr (EMB_ON) {
            const float f0 = PF[er][3], f1 = PF[er][4], f2 = PF[er][5];
            const float pc0 = PF[er][0] + jit, pc1 = PF[er][1] + jit, pc2 = PF[er][2] + jit;
            #pragma unroll
            for (int kt = 0; kt < 12; ++kt) {
                const float pc = (kt>>2)==0 ? pc0 : ((kt>>2)==1 ? pc1 : pc2);
                float v[8];
                #pragma unroll
                for (int i = 0; i < 8; ++i) {
                    const float fr = (kt&1) ? frB[i] : frA[i];
                    const float aa = pc * fr;
                    const float base = ((kt>>1)&1) ? __cosf(aa) : __sinf(aa);
                    const float4 wv = WINT[kt*32 + seg*8 + i];
                    v[i] = fmaf(f0, wv.x, fmaf(f1, wv.y, fmaf(f2, wv.z, base + wv.w)));
                }
                *(bf16x8*)&G[(size_t)(slotbase + kt*64)*8] = pack8(v);
            }
        } else {
            float v[8];
            #pragma unroll
            for (int i = 0; i < 8; ++i) v[i] = 0.5f + jit;
            const bf16x8 cv = pack8(v);
            #pragma unroll
            for (int kt = 0; kt < 12; ++kt)
                *(bf16x8*)&G[(size_t)(slotbase + kt*64)*8] = cv;
        }
        __syncthreads();

        // ---- GEMM phase ----
        f32x4 acc[4][6];
        #pragma unroll
        for (int mt=0; mt<4; ++mt)
            #pragma unroll
            for (int nt=0; nt<6; ++nt)
                acc[mt][nt] = (f32x4){jit, jit, jit, jit};

        if constexpr (GEMM_ON) {
            bf16x8 bA[6], bB[6];
            #define LOADB(dst, kt)                                                      \
                { const unsigned short* bp_ = &W1sf[((size_t)((kt)*24 + ng*6)*64 + l)*8];\
                  _Pragma("unroll")                                                     \
                  for (int nt_ = 0; nt_ < 6; ++nt_)                                     \
                      dst[nt_] = *(const bf16x8*)(bp_ + (size_t)nt_*512); }
            #define AREAD(a_, kt)                                                       \
                { _Pragma("unroll")                                                     \
                  for (int mt_ = 0; mt_ < 4; ++mt_)                                     \
                      a_[mt_] = *(const bf16x8*)&G[(size_t)((((mg*4 + mt_)*12 + (kt))*64) + l)*8]; }
            #define MFMA6(bfr, a_)                                                      \
                { __builtin_amdgcn_s_setprio(1);                                        \
                  _Pragma("unroll")                                                     \
                  for (int mt_ = 0; mt_ < 4; ++mt_)                                     \
                      _Pragma("unroll")                                                 \
                      for (int nt_ = 0; nt_ < 6; ++nt_)                                 \
                          acc[mt_][nt_] = __builtin_amdgcn_mfma_f32_16x16x32_bf16(      \
                              a_[mt_], bfr[nt_], acc[mt_][nt_], 0, 0, 0);               \
                  __builtin_amdgcn_s_setprio(0); }
            LOADB(bA, 0); LOADB(bB, 1);
            #pragma unroll
            for (int kt = 0; kt < 12; kt += 2) {
                bf16x8 a[4];
                AREAD(a, kt);
                MFMA6(bA, a);
                if (kt + 2 < 12) LOADB(bA, kt + 2);
                AREAD(a, kt + 1);
                MFMA6(bB, a);
                if (kt + 3 < 12) LOADB(bB, kt + 3);
            }
            #undef LOADB
            #undef AREAD
            #undef MFMA6
        } else {
            // acc from live data; keep G alive (rule #17)
            #pragma unroll
            for (int mt=0; mt<4; ++mt)
                #pragma unroll
                for (int nt=0; nt<6; ++nt)
                    #pragma unroll
                    for (int r=0; r<4; ++r)
                        acc[mt][nt][r] += dvreg[mt>>1][nt] * 0.125f;
            bf16x8 g = *(const bf16x8*)&G[(size_t)t * 96];
            asm volatile("" :: "v"(g));
        }

        // ---- epilogue: +dstv, gelu, masked mean -> aggpre ----
        float mvr[4][4];
        #pragma unroll
        for (int mt=0; mt<4; ++mt)
            #pragma unroll
            for (int r=0; r<4; ++r)
                mvr[mt][r] = PF[(mg*4 + mt)*16 + lg*4 + r][6];
        #pragma unroll
        for (int nt=0; nt<6; ++nt) {
            const int col = ng*96 + nt*16 + l15;
            float s0 = 0.f, s1 = 0.f;
            #pragma unroll
            for (int mt=0; mt<4; ++mt) {
                const float dv = dvreg[mt>>1][nt];
                float p = 0.f;
                #pragma unroll
                for (int r=0; r<4; ++r)
                    p += mvr[mt][r] * gelu(acc[mt][nt][r] + dv);
                if (mt < 2) s0 += p; else s1 += p;
            }
            s0 += __shfl_xor(s0,16); s0 += __shfl_xor(s0,32);
            s1 += __shfl_xor(s1,16); s1 += __shfl_xor(s1,32);
            if (lg == 0) {
                const int sn0 = bm*4 + mg*2;
                aggpre[(size_t)sn0*HIDDEN + col]     = f2bf(s0 / fmaxf(CNT[mg*2],1.f));
                aggpre[(size_t)(sn0+1)*HIDDEN + col] = f2bf(s1 / fmaxf(CNT[mg*2+1],1.f));
            }
        }
        __syncthreads();   // G reads done before next rep overwrites
    }
    if (t < 4) cntf[bm*4 + t] = CNT[t];
}

__global__ __launch_bounds__(512, 2)
void k_mlp(const float* __restrict__ pos, const float* __restrict__ feat,
           const int* __restrict__ nbr_idx, const void* __restrict__ mask_raw,
           const int* __restrict__ mask_fmt,
           const float* __restrict__ W_in, const float* __restrict__ b_in,
           const float* __restrict__ dstv, const unsigned short* __restrict__ W1sf,
           unsigned short* __restrict__ aggpre, float* __restrict__ cntf) {
    mlp_body<1, true, true>(pos, feat, nbr_idx, mask_raw, mask_fmt,
                            W_in, b_in, dstv, W1sf, aggpre, cntf);
}
__global__ __launch_bounds__(512, 2)
void abl_noE(const float* __restrict__ pos, const float* __restrict__ feat,
             const int* __restrict__ nbr_idx, const void* __restrict__ mask_raw,
             const int* __restrict__ mask_fmt,
             const float* __restrict__ W_in, const float* __restrict__ b_in,
             const float* __restrict__ dstv, const unsigned short* __restrict__ W1sf,
             unsigned short* __restrict__ aggpre, float* __restrict__ cntf) {
    mlp_body<3, false, true>(pos, feat, nbr_idx, mask_raw, mask_fmt,
                             W_in, b_in, dstv, W1sf, aggpre, cntf);
}
__global__ __launch_bounds__(512, 2)
void abl_noG(const float* __restrict__ pos, const float* __restrict__ feat,
             const int* __restrict__ nbr_idx, const void* __restrict__ mask_raw,
             const int* __restrict__ mask_fmt,
             const float* __restrict__ W_in, const float* __restrict__ b_in,
             const float* __restrict__ dstv, const unsigned short* __restrict__ W1sf,
             unsigned short* __restrict__ aggpre, float* __restrict__ cntf) {
    mlp_body<3, true, false>(pos, feat, nbr_idx, mask_raw, mask_fmt,
                             W_in, b_in, dstv, W1sf, aggpre, cntf);
}

// ---- K4: merged agg+proj (unchanged from r14) ----
__global__ __launch_bounds__(256)
void k_out(const unsigned short* __restrict__ aggpre,
           const unsigned short* __restrict__ snxb,
           const unsigned short* __restrict__ w2f,
           const unsigned short* __restrict__ wpf,
           const float* __restrict__ b2, const float* __restrict__ bp,
           const float* __restrict__ cntf, float* __restrict__ out) {
    __shared__ unsigned short AGG[64][392];
    const int rg = blockIdx.x >> 2, cq = blockIdx.x & 3;
    const int t = threadIdx.x, w = t>>6, l = t&63, lg = l>>4, l15 = l&15;
    const int wgm = w>>1, wgn = w&1;
    const int r0g = rg*64;
    {
        const int rowm = wgm*32;
        f32x4 acc[2][12];
        #pragma unroll
        for (int mt=0; mt<2; ++mt)
            #pragma unroll
            for (int nt=0; nt<12; ++nt) acc[mt][nt] = (f32x4){0.f,0.f,0.f,0.f};
        for (int kt = 0; kt < 12; ++kt) {
            bf16x8 a[2], bfr[12];
            const unsigned short* bpp = &w2f[((size_t)(kt*24 + wgn*12)*64 + l)*8];
            #pragma unroll
            for (int nt=0; nt<12; ++nt) bfr[nt] = *(const bf16x8*)(bpp + (size_t)nt*512);
            #pragma unroll
            for (int mt=0; mt<2; ++mt)
                a[mt] = *(const bf16x8*)&aggpre[(size_t)(r0g + rowm + mt*16 + l15)*HIDDEN + kt*32 + lg*8];
            #pragma unroll
            for (int mt=0; mt<2; ++mt)
                #pragma unroll
                for (int nt=0; nt<12; ++nt)
                    acc[mt][nt] = __builtin_amdgcn_mfma_f32_16x16x32_bf16(a[mt], bfr[nt], acc[mt][nt], 0,0,0);
        }
        #pragma unroll
        for (int mt=0; mt<2; ++mt)
            #pragma unroll
            for (int nt=0; nt<12; ++nt) {
                const int col = wgn*192 + nt*16 + l15;
                const float bb = b2[col];
                #pragma unroll
                for (int r=0; r<4; ++r) {
                    const int row = rowm + mt*16 + lg*4 + r;
                    const float nz = (cntf[r0g + row] > 0.f) ? 1.f : 0.f;
                    AGG[row][col] = f2bf(acc[mt][nt][r] + bb*nz);
                }
            }
    }
    __syncthreads();
    const int r0 = r0g + wgm*32;
    const int ntb = cq*6 + wgn*3;
    f32x4 acc[2][3];
    #pragma unroll
    for (int mt=0; mt<2; ++mt)
        #pragma unroll
        for (int nt=0; nt<3; ++nt) acc[mt][nt] = (f32x4){0.f,0.f,0.f,0.f};
    #pragma unroll 2
    for (int kt = 0; kt < 24; ++kt) {
        const unsigned short* Wb = (kt < 12) ? wpf : wpf + WBLK;
        const int ktt = (kt < 12) ? kt : kt - 12;
        bf16x8 a[2], bfr[3];
        const unsigned short* bpp = &Wb[((size_t)(ktt*24 + ntb)*64 + l)*8];
        #pragma unroll
        for (int nt=0; nt<3; ++nt) bfr[nt] = *(const bf16x8*)(bpp + (size_t)nt*512);
        #pragma unroll
        for (int mt=0; mt<2; ++mt) {
            if (kt < 12)
                a[mt] = *(const bf16x8*)&AGG[wgm*32 + mt*16 + l15][ktt*32 + lg*8];
            else
                a[mt] = *(const bf16x8*)&snxb[(size_t)(r0 + mt*16 + l15)*HIDDEN + ktt*32 + lg*8];
        }
        #pragma unroll
        for (int mt=0; mt<2; ++mt)
            #pragma unroll
            for (int nt=0; nt<3; ++nt)
                acc[mt][nt] = __builtin_amdgcn_mfma_f32_16x16x32_bf16(a[mt], bfr[nt], acc[mt][nt], 0,0,0);
    }
    #pragma unroll
    for (int mt=0; mt<2; ++mt)
        #pragma unroll
        for (int nt=0; nt<3; ++nt) {
            const int col = cq*96 + wgn*48 + nt*16 + l15;
            #pragma unroll
            for (int r=0; r<4; ++r) {
                const int row = r0 + mt*16 + lg*4 + r;
                out[(size_t)row*HIDDEN + col] = acc[mt][nt][r] + bp[col];
            }
        }
}

extern "C" void kernel_launch(void* const* d_in, const int* in_sizes, int n_in,
                              void* d_out, int out_size, void* d_ws, size_t ws_size,
                              hipStream_t stream) {
    const float* pos   = (const float*)d_in[0];
    const float* feat  = (const float*)d_in[1];
    const int*   sn    = (const int*)d_in[2];
    const int*   nbr   = (const int*)d_in[3];
    const void*  mask  = d_in[4];
    const float* W_in  = (const float*)d_in[5];
    const float* b_in  = (const float*)d_in[6];
    const float* W1    = (const float*)d_in[7];
    const float* b1    = (const float*)d_in[8];
    const float* W2    = (const float*)d_in[9];
    const float* b2    = (const float*)d_in[10];
    const float* Wp    = (const float*)d_in[11];
    const float* bpv   = (const float*)d_in[12];
    float* out = (float*)d_out;

    char* base = (char*)d_ws;
    int* flag = (int*)base;
    unsigned short* w1sf = (unsigned short*)(base + 256);
    unsigned short* w1df = w1sf + WBLK;
    unsigned short* w2f  = w1df + WBLK;
    unsigned short* wpf  = w2f  + WBLK;
    unsigned short* snxb = wpf  + 2*(size_t)WBLK;
    unsigned short* aggp = snxb + (size_t)NSUPER*HIDDEN;
    float* cntf = (float*)(aggp + (size_t)NSUPER*HIDDEN);
    float* dstv = cntf + NSUPER;
    unsigned short* aggp2 = (unsigned short*)(dstv + (size_t)NSUPER*HIDDEN);
    float* cnt2 = (float*)(aggp2 + (size_t)NSUPER*HIDDEN);

    hipLaunchKernelGGL(prep, dim3(393), dim3(256), 0, stream,
                       W1, W2, Wp, (const unsigned int*)mask,
                       pos, feat, sn, W_in, b_in,
                       w1sf, w1df, w2f, wpf, snxb, flag);
    hipLaunchKernelGGL(k_dstv, dim3(128), dim3(256), 0, stream,
                       snxb, w1df, b1, dstv);
    hipLaunchKernelGGL(k_mlp, dim3(512), dim3(512), 0, stream,
                       pos, feat, nbr, mask, flag, W_in, b_in, dstv,
                       w1sf, aggp, cntf);
    hipLaunchKernelGGL(k_out, dim3(128), dim3(256), 0, stream,
                       aggp, snxb, w2f, wpf, b2, bpv, cntf, out);
    // ---- diagnostics (write only scratch; deterministic) ----
    hipLaunchKernelGGL(abl_noE, dim3(512), dim3(512), 0, stream,
                       pos, feat, nbr, mask, flag, W_in, b_in, dstv,
                       w1sf, aggp2, cnt2);
    hipLaunchKernelGGL(abl_noG, dim3(512), dim3(512), 0, stream,
                       pos, feat, nbr, mask, flag, W_in, b_in, dstv,
                       w1sf, aggp2, cnt2);
}

// Round 16
// 92.492 us; speedup vs baseline: 3.6759x; 3.6759x over previous
//
#include <hip/hip_runtime.h>
#include <hip/hip_bf16.h>
#include <cstdint>

#define HIDDEN 384
#define NSUPER 2048
#define WBLK  (12*24*64*8)          // shorts per 16x16-repacked 384x384 block

typedef __attribute__((ext_vector_type(8)))  short bf16x8;
typedef __attribute__((ext_vector_type(4)))  float f32x4;
typedef __attribute__((ext_vector_type(16))) float f32x16;

// branchless RNE f32->bf16 (finite values only)
__device__ inline unsigned short f2bf(float f) {
    unsigned int u = __float_as_uint(f);
    return (unsigned short)((u + 0x7fffu + ((u >> 16) & 1u)) >> 16);
}
__device__ inline bf16x8 pack8(const float* v) {
    union { bf16x8 v8; unsigned short u[8]; } u;
    #pragma unroll
    for (int i = 0; i < 8; ++i) u.u[i] = f2bf(v[i]);
    return u.v8;
}
// tanh-form gelu via sigmoid: ~9 VALU ops
__device__ inline float gelu(float y) {
    const float y2 = y * y;
    const float m  = __expf(y * fmaf(-0.0713548163f, y2, -1.5957691216f));
    return y * (1.0f / (1.0f + m));
}

// ---- K1: weight repacks + mask detect + supernode embeds ----
// grp0 = W1src in 32x32-frag format (for k_mlp); grps 1..4 in 16x16 format.
__global__ __launch_bounds__(256)
void prep(const float* __restrict__ W1, const float* __restrict__ W2,
          const float* __restrict__ Wp, const unsigned int* __restrict__ mask,
          const float* __restrict__ pos, const float* __restrict__ feat,
          const int* __restrict__ sn_idx,
          const float* __restrict__ W_in, const float* __restrict__ b_in,
          unsigned short* __restrict__ w1s32, unsigned short* __restrict__ w1df,
          unsigned short* __restrict__ w2f,  unsigned short* __restrict__ wpf,
          unsigned short* __restrict__ snxb, int* __restrict__ flag) {
    const int b = blockIdx.x;
    const int t = threadIdx.x;
    if (b == 360) {
        __shared__ int s;
        if (t == 0) s = 0;
        __syncthreads();
        int bad = 0;
        for (int i = t; i < 16384; i += 256)
            if (mask[i] > 1u) bad = 1;
        if (bad) s = 1;
        __syncthreads();
        if (t == 0) *flag = s;   // 1 => uint8, 0 => int32
        return;
    }
    if (b > 360) {    // supernode embeds -> snxb
        __shared__ float W4[HIDDEN][4];
        __shared__ float P6[64][7];
        const int eb = b - 361;
        if (t < 64) {
            const int pi = sn_idx[eb*64 + t];
            P6[t][0]=pos[pi*3];  P6[t][1]=pos[pi*3+1];  P6[t][2]=pos[pi*3+2];
            P6[t][3]=feat[pi*3]; P6[t][4]=feat[pi*3+1]; P6[t][5]=feat[pi*3+2];
        }
        for (int d = t; d < HIDDEN; d += 256) {
            W4[d][0]=W_in[d]; W4[d][1]=W_in[HIDDEN+d];
            W4[d][2]=W_in[2*HIDDEN+d]; W4[d][3]=b_in[d];
        }
        __syncthreads();
        const int er = t >> 2, seg = t & 3;
        float frA[8], frB[8];
        #pragma unroll
        for (int i = 0; i < 8; ++i) {
            frA[i] = exp2f(-(float)(seg*8 + i)      * 0.2076205059304601f);
            frB[i] = exp2f(-(float)(32 + seg*8 + i) * 0.2076205059304601f);
        }
        const float f0 = P6[er][3], f1 = P6[er][4], f2 = P6[er][5];
        #pragma unroll
        for (int cc = 0; cc < 3; ++cc) {
            const float pc = P6[er][cc];
            float sL[8], sH[8], cL[8], cH[8];
            #pragma unroll
            for (int i = 0; i < 8; ++i) {
                const float aL = pc*frA[i], aH = pc*frB[i];
                sL[i]=__sinf(aL); sH[i]=__sinf(aH); cL[i]=__cosf(aL); cH[i]=__cosf(aH);
            }
            #pragma unroll
            for (int q = 0; q < 4; ++q) {
                const float* bb = (q==0)?sL:(q==1)?sH:(q==2)?cL:cH;
                const int blk = cc*4 + q;
                float v[8];
                #pragma unroll
                for (int i = 0; i < 8; ++i) {
                    const int dim = blk*32 + seg*8 + i;
                    const float4 wv = *(const float4*)W4[dim];
                    v[i] = fmaf(f0, wv.x, fmaf(f1, wv.y, fmaf(f2, wv.z, bb[i] + wv.w)));
                }
                *(bf16x8*)&snxb[(size_t)(eb*64 + er)*HIDDEN + blk*32 + seg*8] = pack8(v);
            }
        }
        return;
    }
    const int grp = b / 72, sub = b % 72;
    const int idx = sub * 256 + t;
    const int l   = idx & 63;
    const int frag= idx >> 6;
    const float* W; unsigned short* out;
    int col, k0;
    if (grp == 0) {            // 32x32 frag: kt in [0,24), nt in [0,12)
        W = W1; out = w1s32;
        const int nt = frag % 12, kt = frag / 12;
        col = nt*32 + (l & 31);
        k0  = kt*16 + (l >> 5)*8;
    } else {                   // 16x16 frag: kt in [0,12), nt in [0,24)
        switch (grp) {
            case 1: W = W1 + 384*HIDDEN; out = w1df; break;
            case 2: W = W2;              out = w2f;  break;
            case 3: W = Wp;              out = wpf;  break;
            default:W = Wp + 384*HIDDEN; out = wpf + WBLK; break;
        }
        const int nt = frag % 24, kt = frag / 24;
        col = nt*16 + (l & 15);
        k0  = kt*32 + (l >> 4)*8;
    }
    unsigned int pk[4];
    #pragma unroll
    for (int j = 0; j < 4; ++j) {
        unsigned int lo = f2bf(W[(size_t)(k0 + 2*j)     * HIDDEN + col]);
        unsigned int hi = f2bf(W[(size_t)(k0 + 2*j + 1) * HIDDEN + col]);
        pk[j] = lo | (hi << 16);
    }
    *reinterpret_cast<uint4*>(&out[(size_t)idx * 8]) =
        *reinterpret_cast<const uint4*>(pk);
}

// ---- K2: dstv = snxb @ W1dst + b1 (16x16 path) ----
__global__ __launch_bounds__(256)
void k_dstv(const unsigned short* __restrict__ snxb,
            const unsigned short* __restrict__ w1df,
            const float* __restrict__ b1, float* __restrict__ dstv) {
    const int rg = blockIdx.x >> 2, cq = blockIdx.x & 3;
    const int t = threadIdx.x, w = t>>6, l = t&63, lg = l>>4, l15 = l&15;
    const int wgm = w>>1, wgn = w&1;
    const int r0 = rg*64 + wgm*32;
    const int ntb = cq*6 + wgn*3;
    f32x4 acc[2][3];
    #pragma unroll
    for (int mt=0; mt<2; ++mt)
        #pragma unroll
        for (int nt=0; nt<3; ++nt) acc[mt][nt] = (f32x4){0.f,0.f,0.f,0.f};
    #pragma unroll 2
    for (int kt = 0; kt < 12; ++kt) {
        bf16x8 a[2], bfr[3];
        const unsigned short* bpp = &w1df[((size_t)(kt*24 + ntb)*64 + l)*8];
        #pragma unroll
        for (int nt=0; nt<3; ++nt) bfr[nt] = *(const bf16x8*)(bpp + (size_t)nt*512);
        #pragma unroll
        for (int mt=0; mt<2; ++mt)
            a[mt] = *(const bf16x8*)&snxb[(size_t)(r0 + mt*16 + l15)*HIDDEN + kt*32 + lg*8];
        #pragma unroll
        for (int mt=0; mt<2; ++mt)
            #pragma unroll
            for (int nt=0; nt<3; ++nt)
                acc[mt][nt] = __builtin_amdgcn_mfma_f32_16x16x32_bf16(a[mt], bfr[nt], acc[mt][nt], 0,0,0);
    }
    #pragma unroll
    for (int mt=0; mt<2; ++mt)
        #pragma unroll
        for (int nt=0; nt<3; ++nt) {
            const int col = cq*96 + wgn*48 + nt*16 + l15;
            #pragma unroll
            for (int r=0; r<4; ++r) {
                const int row = r0 + mt*16 + lg*4 + r;
                dstv[(size_t)row*HIDDEN + col] = acc[mt][nt][r] + b1[col];
            }
        }
}

// ---- K3: edge MLP, 1024 thr (16 waves = 4 mg x 4 ng) => 16 waves/CU at the
// same 1-block/CU LDS (2x the residency of every prior round). 32x32x16 MFMA
// halves instruction count and fits the <=128 VGPR requirement of 4 waves/EU.
// Wave (mg,ng): mtile mg (32 rows = exactly supernode bm*4+mg), cols ng*96+96.
__global__ __launch_bounds__(1024)
void k_mlp(const float* __restrict__ pos, const float* __restrict__ feat,
           const int* __restrict__ nbr_idx, const void* __restrict__ mask_raw,
           const int* __restrict__ mask_fmt,
           const float* __restrict__ W_in, const float* __restrict__ b_in,
           const float* __restrict__ dstv,
           const unsigned short* __restrict__ W1s32,
           unsigned short* __restrict__ aggpre, float* __restrict__ cntf)
{
    __shared__ unsigned short G[4*24*64*8];   // 98304 B 32x32-frag-major
    __shared__ float WIN0[HIDDEN], WIN1[HIDDEN], WIN2[HIDDEN], WINB[HIDDEN];
    __shared__ float PF[128][7];
    __shared__ float CNT[4];

    const int t  = threadIdx.x;
    const int bm = blockIdx.x;
    const int l = t & 63, w = t >> 6;
    const int mg = w >> 2, ng = w & 3;

    if (t < 128) {
        const int e  = bm*128 + t;
        const int pi = nbr_idx[e];
        PF[t][0]=pos[pi*3];  PF[t][1]=pos[pi*3+1];  PF[t][2]=pos[pi*3+2];
        PF[t][3]=feat[pi*3]; PF[t][4]=feat[pi*3+1]; PF[t][5]=feat[pi*3+2];
        const int fmt = *mask_fmt;
        const int mv  = fmt ? (int)((const unsigned char*)mask_raw)[e]
                            : ((const int*)mask_raw)[e];
        PF[t][6] = mv ? 1.0f : 0.0f;
    } else if (t >= 128 && t < 128 + HIDDEN) {
        const int d = t - 128;
        WIN0[d] = W_in[d];          WIN1[d] = W_in[HIDDEN + d];
        WIN2[d] = W_in[2*HIDDEN+d]; WINB[d] = b_in[d];
    }
    __syncthreads();
    if (t < 4) {
        float c = 0.f;
        for (int s = 0; s < 32; ++s) c += PF[t*32+s][6];
        CNT[t] = c;   // ordered by the post-embed barrier
    }

    // ---- embed: 8 thr/row; thread (er, seg) covers dims cc*128+sc*64+seg*8+j.
    // kt = cc*8 + sc*4 + (seg>>1); lane = 32*(seg&1) + (er&31);
    // slot = ((er>>5)*24 + kt)*64 + lane  -> one bf16x8 per (cc,sc).
    {
        const int er = t >> 3, seg = t & 7;
        float frS[8];
        #pragma unroll
        for (int j = 0; j < 8; ++j)
            frS[j] = exp2f(-(float)(seg*8 + j) * 0.2076205059304601f);
        const float f0 = PF[er][3], f1 = PF[er][4], f2 = PF[er][5];
        const float pcs[3] = {PF[er][0], PF[er][1], PF[er][2]};
        const int lane = 32*(seg&1) + (er&31);
        const int ktb  = seg >> 1;
        const int mtb  = (er>>5)*24;
        #pragma unroll
        for (int cc = 0; cc < 3; ++cc) {
            const float pc = pcs[cc];
            #pragma unroll
            for (int sc = 0; sc < 2; ++sc) {
                const int kt = cc*8 + sc*4 + ktb;
                float v[8];
                #pragma unroll
                for (int j = 0; j < 8; ++j) {
                    const int dim = cc*128 + sc*64 + seg*8 + j;
                    const float aa = pc * frS[j];
                    const float base = sc ? __cosf(aa) : __sinf(aa);
                    v[j] = fmaf(f0, WIN0[dim], fmaf(f1, WIN1[dim],
                           fmaf(f2, WIN2[dim], base + WINB[dim])));
                }
                *(bf16x8*)&G[(size_t)((mtb + kt)*64 + lane)*8] = pack8(v);
            }
        }
    }
    __syncthreads();

    // ---- GEMM: 24 kt (K=16), 3 ntiles, 32x32x16 MFMA, A+B double-buffered ----
    f32x16 acc[3];
    #pragma unroll
    for (int nt = 0; nt < 3; ++nt)
        #pragma unroll
        for (int r = 0; r < 16; ++r) acc[nt][r] = 0.f;

    bf16x8 bA[3], bB[3], aA, aB;
    #define LOADB(dst, kt)                                                       \
        { const unsigned short* bp_ = &W1s32[((size_t)((kt)*12 + ng*3)*64 + l)*8];\
          _Pragma("unroll")                                                      \
          for (int nt_ = 0; nt_ < 3; ++nt_)                                      \
              dst[nt_] = *(const bf16x8*)(bp_ + (size_t)nt_*512); }
    #define AREAD(kt) (*(const bf16x8*)&G[(size_t)((mg*24 + (kt))*64 + l)*8])
    #define MFMA3(bfr, a_)                                                       \
        { __builtin_amdgcn_s_setprio(1);                                         \
          _Pragma("unroll")                                                      \
          for (int nt_ = 0; nt_ < 3; ++nt_)                                      \
              acc[nt_] = __builtin_amdgcn_mfma_f32_32x32x16_bf16(                \
                  a_, bfr[nt_], acc[nt_], 0, 0, 0);                              \
          __builtin_amdgcn_s_setprio(0); }

    LOADB(bA, 0); LOADB(bB, 1);
    aA = AREAD(0); aB = AREAD(1);
    #pragma unroll
    for (int kt = 0; kt < 24; kt += 2) {
        MFMA3(bA, aA);
        if (kt + 2 < 24) { LOADB(bA, kt + 2); aA = AREAD(kt + 2); }
        MFMA3(bB, aB);
        if (kt + 3 < 24) { LOADB(bB, kt + 3); aB = AREAD(kt + 3); }
    }
    #undef LOADB
    #undef AREAD
    #undef MFMA3

    // ---- epilogue: +dstv, gelu, masked mean over the wave's 32 rows ----
    // C layout (verified m74/m101): col = l&31, row = (r&3)+8*(r>>2)+4*(l>>5).
    const int lh = l >> 5, l31 = l & 31;
    const int sn = bm*4 + mg;
    float dv[3];
    #pragma unroll
    for (int nt = 0; nt < 3; ++nt)
        dv[nt] = dstv[(size_t)sn*HIDDEN + ng*96 + nt*32 + l31];
    float mvr[16];
    #pragma unroll
    for (int r = 0; r < 16; ++r) {
        const int row = (r & 3) + 8*(r >> 2) + 4*lh;
        mvr[r] = PF[mg*32 + row][6];
    }
    const float inv = 1.0f / fmaxf(CNT[mg], 1.f);
    #pragma unroll
    for (int nt = 0; nt < 3; ++nt) {
        float s = 0.f;
        #pragma unroll
        for (int r = 0; r < 16; ++r)
            s += mvr[r] * gelu(acc[nt][r] + dv[nt]);
        s += __shfl_xor(s, 32);
        if (lh == 0)
            aggpre[(size_t)sn*HIDDEN + ng*96 + nt*32 + l31] = f2bf(s * inv);
    }
    if (t < 4) cntf[bm*4 + t] = CNT[t];
}

// ---- K4: merged agg+proj (16x16 path, unchanged) ----
__global__ __launch_bounds__(256)
void k_out(const unsigned short* __restrict__ aggpre,
           const unsigned short* __restrict__ snxb,
           const unsigned short* __restrict__ w2f,
           const unsigned short* __restrict__ wpf,
           const float* __restrict__ b2, const float* __restrict__ bp,
           const float* __restrict__ cntf, float* __restrict__ out) {
    __shared__ unsigned short AGG[64][392];
    const int rg = blockIdx.x >> 2, cq = blockIdx.x & 3;
    const int t = threadIdx.x, w = t>>6, l = t&63, lg = l>>4, l15 = l&15;
    const int wgm = w>>1, wgn = w&1;
    const int r0g = rg*64;
    {
        const int rowm = wgm*32;
        f32x4 acc[2][12];
        #pragma unroll
        for (int mt=0; mt<2; ++mt)
            #pragma unroll
            for (int nt=0; nt<12; ++nt) acc[mt][nt] = (f32x4){0.f,0.f,0.f,0.f};
        for (int kt = 0; kt < 12; ++kt) {
            bf16x8 a[2], bfr[12];
            const unsigned short* bpp = &w2f[((size_t)(kt*24 + wgn*12)*64 + l)*8];
            #pragma unroll
            for (int nt=0; nt<12; ++nt) bfr[nt] = *(const bf16x8*)(bpp + (size_t)nt*512);
            #pragma unroll
            for (int mt=0; mt<2; ++mt)
                a[mt] = *(const bf16x8*)&aggpre[(size_t)(r0g + rowm + mt*16 + l15)*HIDDEN + kt*32 + lg*8];
            #pragma unroll
            for (int mt=0; mt<2; ++mt)
                #pragma unroll
                for (int nt=0; nt<12; ++nt)
                    acc[mt][nt] = __builtin_amdgcn_mfma_f32_16x16x32_bf16(a[mt], bfr[nt], acc[mt][nt], 0,0,0);
        }
        #pragma unroll
        for (int mt=0; mt<2; ++mt)
            #pragma unroll
            for (int nt=0; nt<12; ++nt) {
                const int col = wgn*192 + nt*16 + l15;
                const float bb = b2[col];
                #pragma unroll
                for (int r=0; r<4; ++r) {
                    const int row = rowm + mt*16 + lg*4 + r;
                    const float nz = (cntf[r0g + row] > 0.f) ? 1.f : 0.f;
                    AGG[row][col] = f2bf(acc[mt][nt][r] + bb*nz);
                }
            }
    }
    __syncthreads();
    const int r0 = r0g + wgm*32;
    const int ntb = cq*6 + wgn*3;
    f32x4 acc[2][3];
    #pragma unroll
    for (int mt=0; mt<2; ++mt)
        #pragma unroll
        for (int nt=0; nt<3; ++nt) acc[mt][nt] = (f32x4){0.f,0.f,0.f,0.f};
    #pragma unroll 2
    for (int kt = 0; kt < 24; ++kt) {
        const unsigned short* Wb = (kt < 12) ? wpf : wpf + WBLK;
        const int ktt = (kt < 12) ? kt : kt - 12;
        bf16x8 a[2], bfr[3];
        const unsigned short* bpp = &Wb[((size_t)(ktt*24 + ntb)*64 + l)*8];
        #pragma unroll
        for (int nt=0; nt<3; ++nt) bfr[nt] = *(const bf16x8*)(bpp + (size_t)nt*512);
        #pragma unroll
        for (int mt=0; mt<2; ++mt) {
            if (kt < 12)
                a[mt] = *(const bf16x8*)&AGG[wgm*32 + mt*16 + l15][ktt*32 + lg*8];
            else
                a[mt] = *(const bf16x8*)&snxb[(size_t)(r0 + mt*16 + l15)*HIDDEN + ktt*32 + lg*8];
        }
        #pragma unroll
        for (int mt=0; mt<2; ++mt)
            #pragma unroll
            for (int nt=0; nt<3; ++nt)
                acc[mt][nt] = __builtin_amdgcn_mfma_f32_16x16x32_bf16(a[mt], bfr[nt], acc[mt][nt], 0,0,0);
    }
    #pragma unroll
    for (int mt=0; mt<2; ++mt)
        #pragma unroll
        for (int nt=0; nt<3; ++nt) {
            const int col = cq*96 + wgn*48 + nt*16 + l15;
            #pragma unroll
            for (int r=0; r<4; ++r) {
                const int row = r0 + mt*16 + lg*4 + r;
                out[(size_t)row*HIDDEN + col] = acc[mt][nt][r] + bp[col];
            }
        }
}

extern "C" void kernel_launch(void* const* d_in, const int* in_sizes, int n_in,
                              void* d_out, int out_size, void* d_ws, size_t ws_size,
                              hipStream_t stream) {
    const float* pos   = (const float*)d_in[0];
    const float* feat  = (const float*)d_in[1];
    const int*   sn    = (const int*)d_in[2];
    const int*   nbr   = (const int*)d_in[3];
    const void*  mask  = d_in[4];
    const float* W_in  = (const float*)d_in[5];
    const float* b_in  = (const float*)d_in[6];
    const float* W1    = (const float*)d_in[7];
    const float* b1    = (const float*)d_in[8];
    const float* W2    = (const float*)d_in[9];
    const float* b2    = (const float*)d_in[10];
    const float* Wp    = (const float*)d_in[11];
    const float* bpv   = (const float*)d_in[12];
    float* out = (float*)d_out;

    char* base = (char*)d_ws;
    int* flag = (int*)base;
    unsigned short* w1s32 = (unsigned short*)(base + 256);
    unsigned short* w1df = w1s32 + WBLK;
    unsigned short* w2f  = w1df + WBLK;
    unsigned short* wpf  = w2f  + WBLK;
    unsigned short* snxb = wpf  + 2*(size_t)WBLK;
    unsigned short* aggp = snxb + (size_t)NSUPER*HIDDEN;
    float* cntf = (float*)(aggp + (size_t)NSUPER*HIDDEN);
    float* dstv = cntf + NSUPER;

    hipLaunchKernelGGL(prep, dim3(393), dim3(256), 0, stream,
                       W1, W2, Wp, (const unsigned int*)mask,
                       pos, feat, sn, W_in, b_in,
                       w1s32, w1df, w2f, wpf, snxb, flag);
    hipLaunchKernelGGL(k_dstv, dim3(128), dim3(256), 0, stream,
                       snxb, w1df, b1, dstv);
    hipLaunchKernelGGL(k_mlp, dim3(512), dim3(1024), 0, stream,
                       pos, feat, nbr, mask, flag, W_in, b_in, dstv,
                       w1s32, aggp, cntf);
    hipLaunchKernelGGL(k_out, dim3(128), dim3(256), 0, stream,
                       aggp, snxb, w2f, wpf, b2, bpv, cntf, out);
}

// Round 17
// 90.557 us; speedup vs baseline: 3.7544x; 1.0214x over previous
//
#include <hip/hip_runtime.h>
#include <hip/hip_bf16.h>
#include <cstdint>

#define HIDDEN 384
#define NSUPER 2048
#define WBLK  (12*24*64*8)          // shorts per 16x16-repacked 384x384 block

typedef __attribute__((ext_vector_type(8)))  short bf16x8;
typedef __attribute__((ext_vector_type(4)))  float f32x4;
typedef __attribute__((ext_vector_type(16))) float f32x16;

// branchless RNE f32->bf16 (finite values only)
__device__ inline unsigned short f2bf(float f) {
    unsigned int u = __float_as_uint(f);
    return (unsigned short)((u + 0x7fffu + ((u >> 16) & 1u)) >> 16);
}
__device__ inline bf16x8 pack8(const float* v) {
    union { bf16x8 v8; unsigned short u[8]; } u;
    #pragma unroll
    for (int i = 0; i < 8; ++i) u.u[i] = f2bf(v[i]);
    return u.v8;
}
// tanh-form gelu via sigmoid: ~9 VALU ops
__device__ inline float gelu(float y) {
    const float y2 = y * y;
    const float m  = __expf(y * fmaf(-0.0713548163f, y2, -1.5957691216f));
    return y * (1.0f / (1.0f + m));
}

// ---- K1: weight repacks + mask detect + supernode embeds (r16 version) ----
__global__ __launch_bounds__(256)
void prep(const float* __restrict__ W1, const float* __restrict__ W2,
          const float* __restrict__ Wp, const unsigned int* __restrict__ mask,
          const float* __restrict__ pos, const float* __restrict__ feat,
          const int* __restrict__ sn_idx,
          const float* __restrict__ W_in, const float* __restrict__ b_in,
          unsigned short* __restrict__ w1s32, unsigned short* __restrict__ w1df,
          unsigned short* __restrict__ w2f,  unsigned short* __restrict__ wpf,
          unsigned short* __restrict__ snxb, int* __restrict__ flag) {
    const int b = blockIdx.x;
    const int t = threadIdx.x;
    if (b == 360) {
        __shared__ int s;
        if (t == 0) s = 0;
        __syncthreads();
        int bad = 0;
        for (int i = t; i < 16384; i += 256)
            if (mask[i] > 1u) bad = 1;
        if (bad) s = 1;
        __syncthreads();
        if (t == 0) *flag = s;   // 1 => uint8, 0 => int32
        return;
    }
    if (b > 360) {    // supernode embeds -> snxb
        __shared__ float W4[HIDDEN][4];
        __shared__ float P6[64][7];
        const int eb = b - 361;
        if (t < 64) {
            const int pi = sn_idx[eb*64 + t];
            P6[t][0]=pos[pi*3];  P6[t][1]=pos[pi*3+1];  P6[t][2]=pos[pi*3+2];
            P6[t][3]=feat[pi*3]; P6[t][4]=feat[pi*3+1]; P6[t][5]=feat[pi*3+2];
        }
        for (int d = t; d < HIDDEN; d += 256) {
            W4[d][0]=W_in[d]; W4[d][1]=W_in[HIDDEN+d];
            W4[d][2]=W_in[2*HIDDEN+d]; W4[d][3]=b_in[d];
        }
        __syncthreads();
        const int er = t >> 2, seg = t & 3;
        float frA[8], frB[8];
        #pragma unroll
        for (int i = 0; i < 8; ++i) {
            frA[i] = exp2f(-(float)(seg*8 + i)      * 0.2076205059304601f);
            frB[i] = exp2f(-(float)(32 + seg*8 + i) * 0.2076205059304601f);
        }
        const float f0 = P6[er][3], f1 = P6[er][4], f2 = P6[er][5];
        #pragma unroll
        for (int cc = 0; cc < 3; ++cc) {
            const float pc = P6[er][cc];
            float sL[8], sH[8], cL[8], cH[8];
            #pragma unroll
            for (int i = 0; i < 8; ++i) {
                const float aL = pc*frA[i], aH = pc*frB[i];
                sL[i]=__sinf(aL); sH[i]=__sinf(aH); cL[i]=__cosf(aL); cH[i]=__cosf(aH);
            }
            #pragma unroll
            for (int q = 0; q < 4; ++q) {
                const float* bb = (q==0)?sL:(q==1)?sH:(q==2)?cL:cH;
                const int blk = cc*4 + q;
                float v[8];
                #pragma unroll
                for (int i = 0; i < 8; ++i) {
                    const int dim = blk*32 + seg*8 + i;
                    const float4 wv = *(const float4*)W4[dim];
                    v[i] = fmaf(f0, wv.x, fmaf(f1, wv.y, fmaf(f2, wv.z, bb[i] + wv.w)));
                }
                *(bf16x8*)&snxb[(size_t)(eb*64 + er)*HIDDEN + blk*32 + seg*8] = pack8(v);
            }
        }
        return;
    }
    const int grp = b / 72, sub = b % 72;
    const int idx = sub * 256 + t;
    const int l   = idx & 63;
    const int frag= idx >> 6;
    const float* W; unsigned short* out;
    int col, k0;
    if (grp == 0) {            // 32x32 frag: kt in [0,24), nt in [0,12)
        W = W1; out = w1s32;
        const int nt = frag % 12, kt = frag / 12;
        col = nt*32 + (l & 31);
        k0  = kt*16 + (l >> 5)*8;
    } else {                   // 16x16 frag
        switch (grp) {
            case 1: W = W1 + 384*HIDDEN; out = w1df; break;
            case 2: W = W2;              out = w2f;  break;
            case 3: W = Wp;              out = wpf;  break;
            default:W = Wp + 384*HIDDEN; out = wpf + WBLK; break;
        }
        const int nt = frag % 24, kt = frag / 24;
        col = nt*16 + (l & 15);
        k0  = kt*32 + (l >> 4)*8;
    }
    unsigned int pk[4];
    #pragma unroll
    for (int j = 0; j < 4; ++j) {
        unsigned int lo = f2bf(W[(size_t)(k0 + 2*j)     * HIDDEN + col]);
        unsigned int hi = f2bf(W[(size_t)(k0 + 2*j + 1) * HIDDEN + col]);
        pk[j] = lo | (hi << 16);
    }
    *reinterpret_cast<uint4*>(&out[(size_t)idx * 8]) =
        *reinterpret_cast<const uint4*>(pk);
}

// ---- K2: dstv = snxb @ W1dst + b1 (unchanged) ----
__global__ __launch_bounds__(256)
void k_dstv(const unsigned short* __restrict__ snxb,
            const unsigned short* __restrict__ w1df,
            const float* __restrict__ b1, float* __restrict__ dstv) {
    const int rg = blockIdx.x >> 2, cq = blockIdx.x & 3;
    const int t = threadIdx.x, w = t>>6, l = t&63, lg = l>>4, l15 = l&15;
    const int wgm = w>>1, wgn = w&1;
    const int r0 = rg*64 + wgm*32;
    const int ntb = cq*6 + wgn*3;
    f32x4 acc[2][3];
    #pragma unroll
    for (int mt=0; mt<2; ++mt)
        #pragma unroll
        for (int nt=0; nt<3; ++nt) acc[mt][nt] = (f32x4){0.f,0.f,0.f,0.f};
    #pragma unroll 2
    for (int kt = 0; kt < 12; ++kt) {
        bf16x8 a[2], bfr[3];
        const unsigned short* bpp = &w1df[((size_t)(kt*24 + ntb)*64 + l)*8];
        #pragma unroll
        for (int nt=0; nt<3; ++nt) bfr[nt] = *(const bf16x8*)(bpp + (size_t)nt*512);
        #pragma unroll
        for (int mt=0; mt<2; ++mt)
            a[mt] = *(const bf16x8*)&snxb[(size_t)(r0 + mt*16 + l15)*HIDDEN + kt*32 + lg*8];
        #pragma unroll
        for (int mt=0; mt<2; ++mt)
            #pragma unroll
            for (int nt=0; nt<3; ++nt)
                acc[mt][nt] = __builtin_amdgcn_mfma_f32_16x16x32_bf16(a[mt], bfr[nt], acc[mt][nt], 0,0,0);
    }
    #pragma unroll
    for (int mt=0; mt<2; ++mt)
        #pragma unroll
        for (int nt=0; nt<3; ++nt) {
            const int col = cq*96 + wgn*48 + nt*16 + l15;
            #pragma unroll
            for (int r=0; r<4; ++r) {
                const int row = r0 + mt*16 + lg*4 + r;
                dstv[(size_t)row*HIDDEN + col] = acc[mt][nt][r] + b1[col];
            }
        }
}

// ---- K3: WAVE-SPECIALIZED edge MLP ----
// 1024 thr = 16 waves: w 0..11 = GEMM waves (ntile w, 32 cols), w 12..15 =
// embed waves (one per SIMD via w%4). 64-row half-tiles double-buffered:
//   phase0: embed half0            | (G-waves preload dv)
//   phase1: embed half1            | GEMM+gelu+mean half0
//   phase2: idle                   | GEMM+gelu+mean half1
// Rationale: r15 ablation showed embed(18us) + GEMM(31us) strictly ADD in the
// lockstep structure; m114 says MFMA/feed overlap VALU when waves on the same
// SIMD hold different roles. VALU issue (23.7us measured) is the floor.
__global__ __launch_bounds__(1024)
void k_mlp(const float* __restrict__ pos, const float* __restrict__ feat,
           const int* __restrict__ nbr_idx, const void* __restrict__ mask_raw,
           const int* __restrict__ mask_fmt,
           const float* __restrict__ W_in, const float* __restrict__ b_in,
           const float* __restrict__ dstv,
           const unsigned short* __restrict__ W1s32,
           unsigned short* __restrict__ aggpre, float* __restrict__ cntf)
{
    __shared__ unsigned short G[2][2*24*64*8];   // 2 x 49152 B half-tile bufs
    __shared__ float WIN0[HIDDEN], WIN1[HIDDEN], WIN2[HIDDEN], WINB[HIDDEN];
    __shared__ float PF[128][7];
    __shared__ float CNT[4];

    const int t  = threadIdx.x;
    const int bm = blockIdx.x;
    const int l = t & 63, w = t >> 6;

    if (t < 128) {
        const int e  = bm*128 + t;
        const int pi = nbr_idx[e];
        PF[t][0]=pos[pi*3];  PF[t][1]=pos[pi*3+1];  PF[t][2]=pos[pi*3+2];
        PF[t][3]=feat[pi*3]; PF[t][4]=feat[pi*3+1]; PF[t][5]=feat[pi*3+2];
        const int fmt = *mask_fmt;
        const int mv  = fmt ? (int)((const unsigned char*)mask_raw)[e]
                            : ((const int*)mask_raw)[e];
        PF[t][6] = mv ? 1.0f : 0.0f;
    } else if (t < 128 + HIDDEN) {
        const int d = t - 128;
        WIN0[d] = W_in[d];          WIN1[d] = W_in[HIDDEN + d];
        WIN2[d] = W_in[2*HIDDEN+d]; WINB[d] = b_in[d];
    }
    __syncthreads();
    if (t < 4) {
        float c = 0.f;
        for (int s = 0; s < 32; ++s) c += PF[t*32+s][6];
        CNT[t] = c;   // ordered by phase-0 barrier before first epilogue read
    }

    // ---- embed-wave state (lane: row rl0 = (w-12)*16 + (l&15), chunk ec) ----
    const int ew  = w - 12;
    const int rl0 = ew*16 + (l & 15);
    const int ec  = l >> 4;
    float frL[8], frH[8];
    #pragma unroll
    for (int j = 0; j < 8; ++j) {
        frL[j] = exp2f(-(float)(ec*8 + j)      * 0.2076205059304601f);
        frH[j] = exp2f(-(float)(ec*8 + 32 + j) * 0.2076205059304601f);
    }
    // A-frag map (matches prep grp0 B map): slot (mt,kt,lane) holds
    // row = (lane&31)+mt*32, k = kt*16 + (lane>>5)*8 + j.
    auto embed_half = [&](int h, unsigned short* gb) {
        const int row = h*64 + rl0;
        const float f0 = PF[row][3], f1 = PF[row][4], f2 = PF[row][5];
        const float pcs[3] = {PF[row][0], PF[row][1], PF[row][2]};
        const int mt = rl0 >> 5, r31 = rl0 & 31;
        const int ktc = ec >> 1, hi = ec & 1;
        #pragma unroll
        for (int m = 0; m < 12; ++m) {
            const float pc = pcs[m>>2];
            float v[8];
            #pragma unroll
            for (int j = 0; j < 8; ++j) {
                const float fr = (m & 1) ? frH[j] : frL[j];
                const float aa = pc * fr;
                const float base = ((m>>1) & 1) ? __cosf(aa) : __sinf(aa);
                const int dim = m*32 + ec*8 + j;
                v[j] = fmaf(f0, WIN0[dim], fmaf(f1, WIN1[dim],
                       fmaf(f2, WIN2[dim], base + WINB[dim])));
            }
            const int kt = 2*m + ktc;
            *(bf16x8*)&gb[(size_t)((mt*24 + kt)*64 + 32*hi + r31)*8] = pack8(v);
        }
    };

    // ---- GEMM-wave state ----
    const int nt = w;                // ntile (valid when w < 12)
    const int lh = l >> 5, l31 = l & 31;
    float dv[4] = {0.f, 0.f, 0.f, 0.f};
    if (w < 12) {
        #pragma unroll
        for (int s = 0; s < 4; ++s)
            dv[s] = dstv[(size_t)(bm*4 + s)*HIDDEN + nt*32 + l31];
    }
    auto gemm_half = [&](int h, const unsigned short* gb) {
        f32x16 acc0, acc1;
        #pragma unroll
        for (int r = 0; r < 16; ++r) { acc0[r] = 0.f; acc1[r] = 0.f; }
        bf16x8 bA = *(const bf16x8*)&W1s32[((size_t)(0*12 + nt)*64 + l)*8];
        bf16x8 bB = *(const bf16x8*)&W1s32[((size_t)(1*12 + nt)*64 + l)*8];
        #pragma unroll
        for (int kt = 0; kt < 24; kt += 2) {
            bf16x8 a0 = *(const bf16x8*)&gb[(size_t)(( 0 + kt)*64 + l)*8];
            bf16x8 a1 = *(const bf16x8*)&gb[(size_t)((24 + kt)*64 + l)*8];
            __builtin_amdgcn_s_setprio(1);
            acc0 = __builtin_amdgcn_mfma_f32_32x32x16_bf16(a0, bA, acc0, 0,0,0);
            acc1 = __builtin_amdgcn_mfma_f32_32x32x16_bf16(a1, bA, acc1, 0,0,0);
            __builtin_amdgcn_s_setprio(0);
            if (kt + 2 < 24)
                bA = *(const bf16x8*)&W1s32[((size_t)((kt+2)*12 + nt)*64 + l)*8];
            a0 = *(const bf16x8*)&gb[(size_t)(( 0 + kt+1)*64 + l)*8];
            a1 = *(const bf16x8*)&gb[(size_t)((24 + kt+1)*64 + l)*8];
            __builtin_amdgcn_s_setprio(1);
            acc0 = __builtin_amdgcn_mfma_f32_32x32x16_bf16(a0, bB, acc0, 0,0,0);
            acc1 = __builtin_amdgcn_mfma_f32_32x32x16_bf16(a1, bB, acc1, 0,0,0);
            __builtin_amdgcn_s_setprio(0);
            if (kt + 3 < 24)
                bB = *(const bf16x8*)&W1s32[((size_t)((kt+3)*12 + nt)*64 + l)*8];
        }
        // epilogue: C layout (m74/m101): col=l&31, row=(r&3)+8*(r>>2)+4*(l>>5)
        #pragma unroll
        for (int mt = 0; mt < 2; ++mt) {
            const f32x16 acc = mt ? acc1 : acc0;   // static select (unrolled)
            const int sn    = bm*4 + h*2 + mt;
            const float dvv = dv[h*2 + mt];
            float s = 0.f;
            #pragma unroll
            for (int r = 0; r < 16; ++r) {
                const int rr = (r & 3) + 8*(r >> 2) + 4*lh;
                const float mv = PF[h*64 + mt*32 + rr][6];
                s += mv * gelu(acc[r] + dvv);
            }
            s += __shfl_xor(s, 32);
            if (lh == 0)
                aggpre[(size_t)sn*HIDDEN + nt*32 + l31] =
                    f2bf(s / fmaxf(CNT[h*2 + mt], 1.f));
        }
    };

    // ---- pipeline (barriers at top level: uniform across all waves) ----
    if (w >= 12) embed_half(0, G[0]);
    __syncthreads();
    if (w >= 12) embed_half(1, G[1]);
    else         gemm_half(0, G[0]);
    __syncthreads();
    if (w < 12)  gemm_half(1, G[1]);
    if (t < 4) cntf[bm*4 + t] = CNT[t];
}

// ---- K4: merged agg+proj (unchanged from r16) ----
__global__ __launch_bounds__(256)
void k_out(const unsigned short* __restrict__ aggpre,
           const unsigned short* __restrict__ snxb,
           const unsigned short* __restrict__ w2f,
           const unsigned short* __restrict__ wpf,
           const float* __restrict__ b2, const float* __restrict__ bp,
           const float* __restrict__ cntf, float* __restrict__ out) {
    __shared__ unsigned short AGG[64][392];
    const int rg = blockIdx.x >> 2, cq = blockIdx.x & 3;
    const int t = threadIdx.x, w = t>>6, l = t&63, lg = l>>4, l15 = l&15;
    const int wgm = w>>1, wgn = w&1;
    const int r0g = rg*64;
    {
        const int rowm = wgm*32;
        f32x4 acc[2][12];
        #pragma unroll
        for (int mt=0; mt<2; ++mt)
            #pragma unroll
            for (int nt=0; nt<12; ++nt) acc[mt][nt] = (f32x4){0.f,0.f,0.f,0.f};
        for (int kt = 0; kt < 12; ++kt) {
            bf16x8 a[2], bfr[12];
            const unsigned short* bpp = &w2f[((size_t)(kt*24 + wgn*12)*64 + l)*8];
            #pragma unroll
            for (int nt=0; nt<12; ++nt) bfr[nt] = *(const bf16x8*)(bpp + (size_t)nt*512);
            #pragma unroll
            for (int mt=0; mt<2; ++mt)
                a[mt] = *(const bf16x8*)&aggpre[(size_t)(r0g + rowm + mt*16 + l15)*HIDDEN + kt*32 + lg*8];
            #pragma unroll
            for (int mt=0; mt<2; ++mt)
                #pragma unroll
                for (int nt=0; nt<12; ++nt)
                    acc[mt][nt] = __builtin_amdgcn_mfma_f32_16x16x32_bf16(a[mt], bfr[nt], acc[mt][nt], 0,0,0);
        }
        #pragma unroll
        for (int mt=0; mt<2; ++mt)
            #pragma unroll
            for (int nt=0; nt<12; ++nt) {
                const int col = wgn*192 + nt*16 + l15;
                const float bb = b2[col];
                #pragma unroll
                for (int r=0; r<4; ++r) {
                    const int row = rowm + mt*16 + lg*4 + r;
                    const float nz = (cntf[r0g + row] > 0.f) ? 1.f : 0.f;
                    AGG[row][col] = f2bf(acc[mt][nt][r] + bb*nz);
                }
            }
    }
    __syncthreads();
    const int r0 = r0g + wgm*32;
    const int ntb = cq*6 + wgn*3;
    f32x4 acc[2][3];
    #pragma unroll
    for (int mt=0; mt<2; ++mt)
        #pragma unroll
        for (int nt=0; nt<3; ++nt) acc[mt][nt] = (f32x4){0.f,0.f,0.f,0.f};
    #pragma unroll 2
    for (int kt = 0; kt < 24; ++kt) {
        const unsigned short* Wb = (kt < 12) ? wpf : wpf + WBLK;
        const int ktt = (kt < 12) ? kt : kt - 12;
        bf16x8 a[2], bfr[3];
        const unsigned short* bpp = &Wb[((size_t)(ktt*24 + ntb)*64 + l)*8];
        #pragma unroll
        for (int nt=0; nt<3; ++nt) bfr[nt] = *(const bf16x8*)(bpp + (size_t)nt*512);
        #pragma unroll
        for (int mt=0; mt<2; ++mt) {
            if (kt < 12)
                a[mt] = *(const bf16x8*)&AGG[wgm*32 + mt*16 + l15][ktt*32 + lg*8];
            else
                a[mt] = *(const bf16x8*)&snxb[(size_t)(r0 + mt*16 + l15)*HIDDEN + ktt*32 + lg*8];
        }
        #pragma unroll
        for (int mt=0; mt<2; ++mt)
            #pragma unroll
            for (int nt=0; nt<3; ++nt)
                acc[mt][nt] = __builtin_amdgcn_mfma_f32_16x16x32_bf16(a[mt], bfr[nt], acc[mt][nt], 0,0,0);
    }
    #pragma unroll
    for (int mt=0; mt<2; ++mt)
        #pragma unroll
        for (int nt=0; nt<3; ++nt) {
            const int col = cq*96 + wgn*48 + nt*16 + l15;
            #pragma unroll
            for (int r=0; r<4; ++r) {
                const int row = r0 + mt*16 + lg*4 + r;
                out[(size_t)row*HIDDEN + col] = acc[mt][nt][r] + bp[col];
            }
        }
}

extern "C" void kernel_launch(void* const* d_in, const int* in_sizes, int n_in,
                              void* d_out, int out_size, void* d_ws, size_t ws_size,
                              hipStream_t stream) {
    const float* pos   = (const float*)d_in[0];
    const float* feat  = (const float*)d_in[1];
    const int*   sn    = (const int*)d_in[2];
    const int*   nbr   = (const int*)d_in[3];
    const void*  mask  = d_in[4];
    const float* W_in  = (const float*)d_in[5];
    const float* b_in  = (const float*)d_in[6];
    const float* W1    = (const float*)d_in[7];
    const float* b1    = (const float*)d_in[8];
    const float* W2    = (const float*)d_in[9];
    const float* b2    = (const float*)d_in[10];
    const float* Wp    = (const float*)d_in[11];
    const float* bpv   = (const float*)d_in[12];
    float* out = (float*)d_out;

    char* base = (char*)d_ws;
    int* flag = (int*)base;
    unsigned short* w1s32 = (unsigned short*)(base + 256);
    unsigned short* w1df = w1s32 + WBLK;
    unsigned short* w2f  = w1df + WBLK;
    unsigned short* wpf  = w2f  + WBLK;
    unsigned short* snxb = wpf  + 2*(size_t)WBLK;
    unsigned short* aggp = snxb + (size_t)NSUPER*HIDDEN;
    float* cntf = (float*)(aggp + (size_t)NSUPER*HIDDEN);
    float* dstv = cntf + NSUPER;

    hipLaunchKernelGGL(prep, dim3(393), dim3(256), 0, stream,
                       W1, W2, Wp, (const unsigned int*)mask,
                       pos, feat, sn, W_in, b_in,
                       w1s32, w1df, w2f, wpf, snxb, flag);
    hipLaunchKernelGGL(k_dstv, dim3(128), dim3(256), 0, stream,
                       snxb, w1df, b1, dstv);
    hipLaunchKernelGGL(k_mlp, dim3(512), dim3(1024), 0, stream,
                       pos, feat, nbr, mask, flag, W_in, b_in, dstv,
                       w1s32, aggp, cntf);
    hipLaunchKernelGGL(k_out, dim3(128), dim3(256), 0, stream,
                       aggp, snxb, w2f, wpf, b2, bpv, cntf, out);
}

// Round 18
// 83.563 us; speedup vs baseline: 4.0686x; 1.0837x over previous
//
#include <hip/hip_runtime.h>
#include <hip/hip_bf16.h>
#include <cstdint>

#define HIDDEN 384
#define NSUPER 2048
#define FRAGS (12*24*64)
#define WBLK  (FRAGS*8)             // shorts per repacked 384x384 block = 147456

typedef __attribute__((ext_vector_type(8))) short bf16x8;
typedef __attribute__((ext_vector_type(4))) float f32x4;

// branchless RNE f32->bf16 (finite values only)
__device__ inline unsigned short f2bf(float f) {
    unsigned int u = __float_as_uint(f);
    return (unsigned short)((u + 0x7fffu + ((u >> 16) & 1u)) >> 16);
}
__device__ inline float b2f(unsigned short s) {
    return __uint_as_float(((unsigned int)s) << 16);
}
__device__ inline bf16x8 pack8(const float* v) {
    union { bf16x8 v8; unsigned short u[8]; } u;
    #pragma unroll
    for (int i = 0; i < 8; ++i) u.u[i] = f2bf(v[i]);
    return u.v8;
}
// tanh-form gelu via sigmoid: ~9 VALU ops, |err| <= ~1e-3 on gelu
__device__ inline float gelu(float y) {
    const float y2 = y * y;
    const float m  = __expf(y * fmaf(-0.0713548163f, y2, -1.5957691216f));
    return y * (1.0f / (1.0f + m));
}

// ---- K1: weight repacks + mask detect + supernode embeds (r11 verbatim) ----
__global__ __launch_bounds__(256)
void prep(const float* __restrict__ W1, const float* __restrict__ W2,
          const float* __restrict__ Wp, const unsigned int* __restrict__ mask,
          const float* __restrict__ pos, const float* __restrict__ feat,
          const int* __restrict__ sn_idx,
          const float* __restrict__ W_in, const float* __restrict__ b_in,
          unsigned short* __restrict__ w1sf, unsigned short* __restrict__ w1df,
          unsigned short* __restrict__ w2f,  unsigned short* __restrict__ wpf,
          unsigned short* __restrict__ snxb, int* __restrict__ flag) {
    const int b = blockIdx.x;
    const int t = threadIdx.x;
    if (b == 360) {   // mask detect: uint8 numpy-bool vs int32
        __shared__ int s;
        if (t == 0) s = 0;
        __syncthreads();
        int bad = 0;
        for (int i = t; i < 16384; i += 256)
            if (mask[i] > 1u) bad = 1;
        if (bad) s = 1;
        __syncthreads();
        if (t == 0) *flag = s;   // 1 => uint8, 0 => int32
        return;
    }
    if (b > 360) {    // ---- supernode embeds -> snxb ----
        __shared__ float W4[HIDDEN][4];
        __shared__ float P6[64][7];
        const int eb = b - 361;   // 0..31
        if (t < 64) {
            const int pi = sn_idx[eb*64 + t];
            P6[t][0]=pos[pi*3];  P6[t][1]=pos[pi*3+1];  P6[t][2]=pos[pi*3+2];
            P6[t][3]=feat[pi*3]; P6[t][4]=feat[pi*3+1]; P6[t][5]=feat[pi*3+2];
        }
        for (int d = t; d < HIDDEN; d += 256) {
            W4[d][0]=W_in[d]; W4[d][1]=W_in[HIDDEN+d];
            W4[d][2]=W_in[2*HIDDEN+d]; W4[d][3]=b_in[d];
        }
        __syncthreads();
        const int er = t >> 2, seg = t & 3;
        float frA[8], frB[8];
        #pragma unroll
        for (int i = 0; i < 8; ++i) {
            frA[i] = exp2f(-(float)(seg*8 + i)      * 0.2076205059304601f);
            frB[i] = exp2f(-(float)(32 + seg*8 + i) * 0.2076205059304601f);
        }
        const float f0 = P6[er][3], f1 = P6[er][4], f2 = P6[er][5];
        #pragma unroll
        for (int cc = 0; cc < 3; ++cc) {
            const float pc = P6[er][cc];
            float sL[8], sH[8], cL[8], cH[8];
            #pragma unroll
            for (int i = 0; i < 8; ++i) {
                const float aL = pc*frA[i], aH = pc*frB[i];
                sL[i]=__sinf(aL); sH[i]=__sinf(aH); cL[i]=__cosf(aL); cH[i]=__cosf(aH);
            }
            #pragma unroll
            for (int q = 0; q < 4; ++q) {
                const float* bb = (q==0)?sL:(q==1)?sH:(q==2)?cL:cH;
                const int blk = cc*4 + q;
                float v[8];
                #pragma unroll
                for (int i = 0; i < 8; ++i) {
                    const int dim = blk*32 + seg*8 + i;
                    const float4 wv = *(const float4*)W4[dim];
                    v[i] = fmaf(f0, wv.x, fmaf(f1, wv.y, fmaf(f2, wv.z, bb[i] + wv.w)));
                }
                *(bf16x8*)&snxb[(size_t)(eb*64 + er)*HIDDEN + blk*32 + seg*8] = pack8(v);
            }
        }
        return;
    }
    // ---- repack: frag (kt,nt): lane l elem j = W[kt*32+(l>>4)*8+j][nt*16+(l&15)]
    const int grp = b / 72, sub = b % 72;
    const float* W; unsigned short* out;
    switch (grp) {
        case 0: W = W1;              out = w1sf; break;
        case 1: W = W1 + 384*HIDDEN; out = w1df; break;
        case 2: W = W2;              out = w2f;  break;
        case 3: W = Wp;              out = wpf;  break;
        default:W = Wp + 384*HIDDEN; out = wpf + WBLK; break;
    }
    const int idx = sub * 256 + t;   // 72*256 == FRAGS exactly
    const int l   = idx & 63;
    const int frag= idx >> 6;
    const int nt  = frag % 24;
    const int kt  = frag / 24;
    const int col = nt * 16 + (l & 15);
    const int k0  = kt * 32 + (l >> 4) * 8;
    unsigned int pk[4];
    #pragma unroll
    for (int j = 0; j < 4; ++j) {
        unsigned int lo = f2bf(W[(size_t)(k0 + 2*j)     * HIDDEN + col]);
        unsigned int hi = f2bf(W[(size_t)(k0 + 2*j + 1) * HIDDEN + col]);
        pk[j] = lo | (hi << 16);
    }
    *reinterpret_cast<uint4*>(&out[(size_t)idx * 8]) =
        *reinterpret_cast<const uint4*>(pk);
}

// ---- K2: fused edge MLP (r11 verbatim): layer-1 with K=768 dst-fold +
// gelu + masked mean -> aggpre. 256 thr, 1024 blocks, 54 KB LDS. ----
__global__ __launch_bounds__(256, 2)
void k_mlp(const float* __restrict__ pos, const float* __restrict__ feat,
           const int* __restrict__ nbr_idx, const void* __restrict__ mask_raw,
           const int* __restrict__ mask_fmt,
           const float* __restrict__ W_in, const float* __restrict__ b_in,
           const unsigned short* __restrict__ snxb,
           const unsigned short* __restrict__ W1sf,
           const unsigned short* __restrict__ W1df,
           const float* __restrict__ b1,
           unsigned short* __restrict__ aggpre, float* __restrict__ cntf)
{
    __shared__ unsigned short G[4*12*64*8];   // 49152 B frag-major embeds
    __shared__ ushort4 WINTB[HIDDEN];         // 3072 B bf16 {w0,w1,w2,b}
    __shared__ float PF[64][7];               // 1792 B pos3,feat3,mval
    __shared__ float CNT[2];

    const int t  = threadIdx.x;
    const int bm = blockIdx.x;
    const int l = t & 63, ng = t >> 6, lg = l >> 4, l15 = l & 15;

    bf16x8 bA[6], bB[6];
    #define LOADB(dst, Wf, kt)                                                  \
        { const unsigned short* bp_ = &Wf[((size_t)((kt)*24 + ng*6)*64 + l)*8]; \
          _Pragma("unroll")                                                     \
          for (int nt_ = 0; nt_ < 6; ++nt_)                                     \
              dst[nt_] = *(const bf16x8*)(bp_ + (size_t)nt_*512); }
    #define AREAD(a_, kt)                                                       \
        { _Pragma("unroll")                                                     \
          for (int mt_ = 0; mt_ < 4; ++mt_)                                     \
              a_[mt_] = *(const bf16x8*)&G[(size_t)(((mt_*12 + (kt))*64) + l)*8]; }
    #define MFMA6(bfr, a_)                                                      \
        { __builtin_amdgcn_s_setprio(1);                                        \
          _Pragma("unroll")                                                     \
          for (int mt_ = 0; mt_ < 4; ++mt_)                                     \
              _Pragma("unroll")                                                 \
              for (int nt_ = 0; nt_ < 6; ++nt_)                                 \
                  acc[mt_][nt_] = __builtin_amdgcn_mfma_f32_16x16x32_bf16(      \
                      a_[mt_], bfr[nt_], acc[mt_][nt_], 0, 0, 0);               \
          __builtin_amdgcn_s_setprio(0); }

    if (t < 64) {
        const int e  = bm*64 + t;
        const int pi = nbr_idx[e];
        PF[t][0]=pos[pi*3];  PF[t][1]=pos[pi*3+1];  PF[t][2]=pos[pi*3+2];
        PF[t][3]=feat[pi*3]; PF[t][4]=feat[pi*3+1]; PF[t][5]=feat[pi*3+2];
        const int fmt = *mask_fmt;
        const int mv  = fmt ? (int)((const unsigned char*)mask_raw)[e]
                            : ((const int*)mask_raw)[e];
        PF[t][6] = mv ? 1.0f : 0.0f;
    }
    for (int d = t; d < HIDDEN; d += 256) {
        ushort4 wv;
        wv.x = f2bf(W_in[d]); wv.y = f2bf(W_in[HIDDEN+d]);
        wv.z = f2bf(W_in[2*HIDDEN+d]); wv.w = f2bf(b_in[d]);
        WINTB[d] = wv;
    }
    float b1r[6];
    #pragma unroll
    for (int nt = 0; nt < 6; ++nt) b1r[nt] = b1[ng*96 + nt*16 + l15];
    __syncthreads();
    if (t < 2) {
        float c = 0.f;
        for (int s = 0; s < 32; ++s) c += PF[t*32+s][6];
        CNT[t] = c;   // read after the phase-A barrier
    }

    const int er = t >> 2, seg = t & 3;
    float frA[8], frB[8];
    #pragma unroll
    for (int i = 0; i < 8; ++i) {
        frA[i] = exp2f(-(float)(seg*8 + i)      * 0.2076205059304601f);
        frB[i] = exp2f(-(float)(32 + seg*8 + i) * 0.2076205059304601f);
    }
    const float f0 = PF[er][3], f1 = PF[er][4], f2 = PF[er][5];
    const float pc0 = PF[er][0], pc1 = PF[er][1], pc2 = PF[er][2];
    const int slotbase = (er>>4)*12*64 + seg*16 + (er&15);

    #define EMB(kt_)                                                            \
        { const float pc = ((kt_)>>2)==0 ? pc0 : (((kt_)>>2)==1 ? pc1 : pc2);   \
          float v[8];                                                           \
          _Pragma("unroll")                                                     \
          for (int i = 0; i < 8; ++i) {                                         \
              const float fr = ((kt_)&1) ? frB[i] : frA[i];                     \
              const float aa = pc * fr;                                         \
              const float base = (((kt_)>>1)&1) ? __cosf(aa) : __sinf(aa);      \
              const ushort4 wv = WINTB[(kt_)*32 + seg*8 + i];                   \
              v[i] = fmaf(f0, b2f(wv.x), fmaf(f1, b2f(wv.y),                    \
                     fmaf(f2, b2f(wv.z), base + b2f(wv.w))));                   \
          }                                                                     \
          *(bf16x8*)&G[(size_t)(slotbase + (kt_)*64)*8] = pack8(v); }

    f32x4 acc[4][6];
    #pragma unroll
    for (int mt=0; mt<4; ++mt)
        #pragma unroll
        for (int nt=0; nt<6; ++nt) acc[mt][nt] = (f32x4){0.f,0.f,0.f,0.f};

    // ---- phase A: dst-half GEMM (snxb broadcast A) interleaved with embed ----
    const unsigned short* snx0 = &snxb[(size_t)(bm*2 + 0)*HIDDEN];
    const unsigned short* snx1 = &snxb[(size_t)(bm*2 + 1)*HIDDEN];
    #pragma unroll
    for (int kt = 0; kt < 12; ++kt) {
        LOADB(bA, W1df, kt);
        bf16x8 s0 = *(const bf16x8*)&snx0[kt*32 + lg*8];
        bf16x8 s1 = *(const bf16x8*)&snx1[kt*32 + lg*8];
        EMB(kt);
        __builtin_amdgcn_s_setprio(1);
        #pragma unroll
        for (int nt = 0; nt < 6; ++nt) {
            acc[0][nt] = __builtin_amdgcn_mfma_f32_16x16x32_bf16(s0, bA[nt], acc[0][nt], 0,0,0);
            acc[1][nt] = __builtin_amdgcn_mfma_f32_16x16x32_bf16(s0, bA[nt], acc[1][nt], 0,0,0);
            acc[2][nt] = __builtin_amdgcn_mfma_f32_16x16x32_bf16(s1, bA[nt], acc[2][nt], 0,0,0);
            acc[3][nt] = __builtin_amdgcn_mfma_f32_16x16x32_bf16(s1, bA[nt], acc[3][nt], 0,0,0);
        }
        __builtin_amdgcn_s_setprio(0);
    }
    __syncthreads();   // G complete (also orders CNT)

    // ---- phase B: src-half GEMM from LDS, B 2-deep prefetch ----
    LOADB(bA, W1sf, 0); LOADB(bB, W1sf, 1);
    #pragma unroll
    for (int kt = 0; kt < 12; kt += 2) {
        bf16x8 a[4];
        AREAD(a, kt);
        MFMA6(bA, a);
        if (kt + 2 < 12) LOADB(bA, W1sf, kt + 2);
        AREAD(a, kt + 1);
        MFMA6(bB, a);
        if (kt + 3 < 12) LOADB(bB, W1sf, kt + 3);
    }

    // ---- gelu + masked mean -> aggpre ----
    float mvr[4][4];
    #pragma unroll
    for (int mt=0; mt<4; ++mt)
        #pragma unroll
        for (int r=0; r<4; ++r)
            mvr[mt][r] = PF[mt*16 + lg*4 + r][6];
    #pragma unroll
    for (int nt=0; nt<6; ++nt) {
        const int col = ng*96 + nt*16 + l15;
        const float bb1 = b1r[nt];
        float s0 = 0.f, s1 = 0.f;
        #pragma unroll
        for (int mt=0; mt<4; ++mt) {
            float p = 0.f;
            #pragma unroll
            for (int r=0; r<4; ++r)
                p += mvr[mt][r] * gelu(acc[mt][nt][r] + bb1);
            if (mt < 2) s0 += p; else s1 += p;
        }
        s0 += __shfl_xor(s0,16); s0 += __shfl_xor(s0,32);
        s1 += __shfl_xor(s1,16); s1 += __shfl_xor(s1,32);
        if (lg == 0) {
            const int sn0 = bm*2;
            aggpre[(size_t)sn0*HIDDEN + col]     = f2bf(s0 / fmaxf(CNT[0],1.f));
            aggpre[(size_t)(sn0+1)*HIDDEN + col] = f2bf(s1 / fmaxf(CNT[1],1.f));
        }
    }
    if (t < 2) cntf[bm*2 + t] = CNT[t];
    #undef LOADB
    #undef AREAD
    #undef MFMA6
    #undef EMB
}

// ---- K3: merged agg+proj (r14 verbatim) ----
__global__ __launch_bounds__(256)
void k_out(const unsigned short* __restrict__ aggpre,
           const unsigned short* __restrict__ snxb,
           const unsigned short* __restrict__ w2f,
           const unsigned short* __restrict__ wpf,
           const float* __restrict__ b2, const float* __restrict__ bp,
           const float* __restrict__ cntf, float* __restrict__ out) {
    __shared__ unsigned short AGG[64][392];   // 50176 B
    const int rg = blockIdx.x >> 2, cq = blockIdx.x & 3;
    const int t = threadIdx.x, w = t>>6, l = t&63, lg = l>>4, l15 = l&15;
    const int wgm = w>>1, wgn = w&1;
    const int r0g = rg*64;

    // phase 1: AGG[64][384] = aggpre(rows) @ W2 + b2*nz into LDS
    {
        const int rowm = wgm*32;
        f32x4 acc[2][12];
        #pragma unroll
        for (int mt=0; mt<2; ++mt)
            #pragma unroll
            for (int nt=0; nt<12; ++nt) acc[mt][nt] = (f32x4){0.f,0.f,0.f,0.f};
        for (int kt = 0; kt < 12; ++kt) {
            bf16x8 a[2], bfr[12];
            const unsigned short* bpp = &w2f[((size_t)(kt*24 + wgn*12)*64 + l)*8];
            #pragma unroll
            for (int nt=0; nt<12; ++nt) bfr[nt] = *(const bf16x8*)(bpp + (size_t)nt*512);
            #pragma unroll
            for (int mt=0; mt<2; ++mt)
                a[mt] = *(const bf16x8*)&aggpre[(size_t)(r0g + rowm + mt*16 + l15)*HIDDEN + kt*32 + lg*8];
            #pragma unroll
            for (int mt=0; mt<2; ++mt)
                #pragma unroll
                for (int nt=0; nt<12; ++nt)
                    acc[mt][nt] = __builtin_amdgcn_mfma_f32_16x16x32_bf16(a[mt], bfr[nt], acc[mt][nt], 0,0,0);
        }
        #pragma unroll
        for (int mt=0; mt<2; ++mt)
            #pragma unroll
            for (int nt=0; nt<12; ++nt) {
                const int col = wgn*192 + nt*16 + l15;
                const float bb = b2[col];
                #pragma unroll
                for (int r=0; r<4; ++r) {
                    const int row = rowm + mt*16 + lg*4 + r;
                    const float nz = (cntf[r0g + row] > 0.f) ? 1.f : 0.f;
                    AGG[row][col] = f2bf(acc[mt][nt][r] + bb*nz);
                }
            }
    }
    __syncthreads();

    // phase 2: out rows x (cq*96 + wgn*48) cols = [AGG | snxb] @ Wp + bp
    const int r0 = r0g + wgm*32;
    const int ntb = cq*6 + wgn*3;
    f32x4 acc[2][3];
    #pragma unroll
    for (int mt=0; mt<2; ++mt)
        #pragma unroll
        for (int nt=0; nt<3; ++nt) acc[mt][nt] = (f32x4){0.f,0.f,0.f,0.f};
    #pragma unroll 2
    for (int kt = 0; kt < 24; ++kt) {
        const unsigned short* Wb = (kt < 12) ? wpf : wpf + WBLK;
        const int ktt = (kt < 12) ? kt : kt - 12;
        bf16x8 a[2], bfr[3];
        const unsigned short* bpp = &Wb[((size_t)(ktt*24 + ntb)*64 + l)*8];
        #pragma unroll
        for (int nt=0; nt<3; ++nt) bfr[nt] = *(const bf16x8*)(bpp + (size_t)nt*512);
        #pragma unroll
        for (int mt=0; mt<2; ++mt) {
            if (kt < 12)
                a[mt] = *(const bf16x8*)&AGG[wgm*32 + mt*16 + l15][ktt*32 + lg*8];
            else
                a[mt] = *(const bf16x8*)&snxb[(size_t)(r0 + mt*16 + l15)*HIDDEN + ktt*32 + lg*8];
        }
        #pragma unroll
        for (int mt=0; mt<2; ++mt)
            #pragma unroll
            for (int nt=0; nt<3; ++nt)
                acc[mt][nt] = __builtin_amdgcn_mfma_f32_16x16x32_bf16(a[mt], bfr[nt], acc[mt][nt], 0,0,0);
    }
    #pragma unroll
    for (int mt=0; mt<2; ++mt)
        #pragma unroll
        for (int nt=0; nt<3; ++nt) {
            const int col = cq*96 + wgn*48 + nt*16 + l15;
            #pragma unroll
            for (int r=0; r<4; ++r) {
                const int row = r0 + mt*16 + lg*4 + r;
                out[(size_t)row*HIDDEN + col] = acc[mt][nt][r] + bp[col];
            }
        }
}

extern "C" void kernel_launch(void* const* d_in, const int* in_sizes, int n_in,
                              void* d_out, int out_size, void* d_ws, size_t ws_size,
                              hipStream_t stream) {
    const float* pos   = (const float*)d_in[0];
    const float* feat  = (const float*)d_in[1];
    const int*   sn    = (const int*)d_in[2];
    const int*   nbr   = (const int*)d_in[3];
    const void*  mask  = d_in[4];
    const float* W_in  = (const float*)d_in[5];
    const float* b_in  = (const float*)d_in[6];
    const float* W1    = (const float*)d_in[7];
    const float* b1    = (const float*)d_in[8];
    const float* W2    = (const float*)d_in[9];
    const float* b2    = (const float*)d_in[10];
    const float* Wp    = (const float*)d_in[11];
    const float* bpv   = (const float*)d_in[12];
    float* out = (float*)d_out;

    char* base = (char*)d_ws;
    int* flag = (int*)base;
    unsigned short* w1sf = (unsigned short*)(base + 256);
    unsigned short* w1df = w1sf + WBLK;
    unsigned short* w2f  = w1df + WBLK;
    unsigned short* wpf  = w2f  + WBLK;                  // 2 blocks (768 rows)
    unsigned short* snxb = wpf  + 2*(size_t)WBLK;        // 2048*384 bf16
    unsigned short* aggp = snxb + (size_t)NSUPER*HIDDEN; // 2048*384 bf16
    float* cntf = (float*)(aggp + (size_t)NSUPER*HIDDEN); // 2048 f32

    hipLaunchKernelGGL(prep, dim3(393), dim3(256), 0, stream,
                       W1, W2, Wp, (const unsigned int*)mask,
                       pos, feat, sn, W_in, b_in,
                       w1sf, w1df, w2f, wpf, snxb, flag);
    hipLaunchKernelGGL(k_mlp, dim3(1024), dim3(256), 0, stream,
                       pos, feat, nbr, mask, flag, W_in, b_in,
                       snxb, w1sf, w1df, b1, aggp, cntf);
    hipLaunchKernelGGL(k_out, dim3(128), dim3(256), 0, stream,
                       aggp, snxb, w2f, wpf, b2, bpv, cntf, out);
}

// Round 19
// 82.037 us; speedup vs baseline: 4.1443x; 1.0186x over previous
//
#include <hip/hip_runtime.h>
#include <hip/hip_bf16.h>
#include <cstdint>

#define HIDDEN 384
#define NSUPER 2048
#define FRAGS (12*24*64)
#define WBLK  (FRAGS*8)             // shorts per repacked 384x384 block = 147456

typedef __attribute__((ext_vector_type(8))) short bf16x8;
typedef __attribute__((ext_vector_type(4))) float f32x4;

// branchless RNE f32->bf16 (finite values only)
__device__ inline unsigned short f2bf(float f) {
    unsigned int u = __float_as_uint(f);
    return (unsigned short)((u + 0x7fffu + ((u >> 16) & 1u)) >> 16);
}
__device__ inline float b2f(unsigned short s) {
    return __uint_as_float(((unsigned int)s) << 16);
}
__device__ inline bf16x8 pack8(const float* v) {
    union { bf16x8 v8; unsigned short u[8]; } u;
    #pragma unroll
    for (int i = 0; i < 8; ++i) u.u[i] = f2bf(v[i]);
    return u.v8;
}
// tanh-form gelu via sigmoid: ~9 VALU ops, |err| <= ~1e-3 on gelu
__device__ inline float gelu(float y) {
    const float y2 = y * y;
    const float m  = __expf(y * fmaf(-0.0713548163f, y2, -1.5957691216f));
    return y * (1.0f / (1.0f + m));
}

// ---- K1: supernode embeds (blocks 0..31, FIRST: heavy trig on the critical
// path) + weight repacks (32..391) + mask detect (392) ----
__global__ __launch_bounds__(256)
void prep(const float* __restrict__ W1, const float* __restrict__ W2,
          const float* __restrict__ Wp, const unsigned int* __restrict__ mask,
          const float* __restrict__ pos, const float* __restrict__ feat,
          const int* __restrict__ sn_idx,
          const float* __restrict__ W_in, const float* __restrict__ b_in,
          unsigned short* __restrict__ w1sf, unsigned short* __restrict__ w1df,
          unsigned short* __restrict__ w2f,  unsigned short* __restrict__ wpf,
          unsigned short* __restrict__ snxb, int* __restrict__ flag) {
    const int b = blockIdx.x;
    const int t = threadIdx.x;
    if (b == 392) {   // mask detect: uint8 numpy-bool vs int32
        __shared__ int s;
        if (t == 0) s = 0;
        __syncthreads();
        int bad = 0;
        for (int i = t; i < 16384; i += 256)
            if (mask[i] > 1u) bad = 1;
        if (bad) s = 1;
        __syncthreads();
        if (t == 0) *flag = s;   // 1 => uint8, 0 => int32
        return;
    }
    if (b < 32) {     // ---- supernode embeds -> snxb ----
        __shared__ float W4[HIDDEN][4];
        __shared__ float P6[64][7];
        const int eb = b;   // 0..31
        if (t < 64) {
            const int pi = sn_idx[eb*64 + t];
            P6[t][0]=pos[pi*3];  P6[t][1]=pos[pi*3+1];  P6[t][2]=pos[pi*3+2];
            P6[t][3]=feat[pi*3]; P6[t][4]=feat[pi*3+1]; P6[t][5]=feat[pi*3+2];
        }
        for (int d = t; d < HIDDEN; d += 256) {
            W4[d][0]=W_in[d]; W4[d][1]=W_in[HIDDEN+d];
            W4[d][2]=W_in[2*HIDDEN+d]; W4[d][3]=b_in[d];
        }
        __syncthreads();
        const int er = t >> 2, seg = t & 3;
        float frA[8], frB[8];
        #pragma unroll
        for (int i = 0; i < 8; ++i) {
            frA[i] = exp2f(-(float)(seg*8 + i)      * 0.2076205059304601f);
            frB[i] = exp2f(-(float)(32 + seg*8 + i) * 0.2076205059304601f);
        }
        const float f0 = P6[er][3], f1 = P6[er][4], f2 = P6[er][5];
        #pragma unroll
        for (int cc = 0; cc < 3; ++cc) {
            const float pc = P6[er][cc];
            float sL[8], sH[8], cL[8], cH[8];
            #pragma unroll
            for (int i = 0; i < 8; ++i) {
                const float aL = pc*frA[i], aH = pc*frB[i];
                sL[i]=__sinf(aL); sH[i]=__sinf(aH); cL[i]=__cosf(aL); cH[i]=__cosf(aH);
            }
            #pragma unroll
            for (int q = 0; q < 4; ++q) {
                const float* bb = (q==0)?sL:(q==1)?sH:(q==2)?cL:cH;
                const int blk = cc*4 + q;
                float v[8];
                #pragma unroll
                for (int i = 0; i < 8; ++i) {
                    const int dim = blk*32 + seg*8 + i;
                    const float4 wv = *(const float4*)W4[dim];
                    v[i] = fmaf(f0, wv.x, fmaf(f1, wv.y, fmaf(f2, wv.z, bb[i] + wv.w)));
                }
                *(bf16x8*)&snxb[(size_t)(eb*64 + er)*HIDDEN + blk*32 + seg*8] = pack8(v);
            }
        }
        return;
    }
    // ---- repack: frag (kt,nt): lane l elem j = W[kt*32+(l>>4)*8+j][nt*16+(l&15)]
    const int rb  = b - 32;                 // 0..359
    const int grp = rb / 72, sub = rb % 72;
    const float* W; unsigned short* out;
    switch (grp) {
        case 0: W = W1;              out = w1sf; break;
        case 1: W = W1 + 384*HIDDEN; out = w1df; break;
        case 2: W = W2;              out = w2f;  break;
        case 3: W = Wp;              out = wpf;  break;
        default:W = Wp + 384*HIDDEN; out = wpf + WBLK; break;
    }
    const int idx = sub * 256 + t;   // 72*256 == FRAGS exactly
    const int l   = idx & 63;
    const int frag= idx >> 6;
    const int nt  = frag % 24;
    const int kt  = frag / 24;
    const int col = nt * 16 + (l & 15);
    const int k0  = kt * 32 + (l >> 4) * 8;
    unsigned int pk[4];
    #pragma unroll
    for (int j = 0; j < 4; ++j) {
        unsigned int lo = f2bf(W[(size_t)(k0 + 2*j)     * HIDDEN + col]);
        unsigned int hi = f2bf(W[(size_t)(k0 + 2*j + 1) * HIDDEN + col]);
        pk[j] = lo | (hi << 16);
    }
    *reinterpret_cast<uint4*>(&out[(size_t)idx * 8]) =
        *reinterpret_cast<const uint4*>(pk);
}

// ---- K2: fused edge MLP (r11/r18-verified): layer-1 with K=768 dst-fold +
// gelu + masked mean -> aggpre. 256 thr, 1024 blocks, 54 KB LDS. ----
__global__ __launch_bounds__(256, 2)
void k_mlp(const float* __restrict__ pos, const float* __restrict__ feat,
           const int* __restrict__ nbr_idx, const void* __restrict__ mask_raw,
           const int* __restrict__ mask_fmt,
           const float* __restrict__ W_in, const float* __restrict__ b_in,
           const unsigned short* __restrict__ snxb,
           const unsigned short* __restrict__ W1sf,
           const unsigned short* __restrict__ W1df,
           const float* __restrict__ b1,
           unsigned short* __restrict__ aggpre, float* __restrict__ cntf)
{
    __shared__ unsigned short G[4*12*64*8];   // 49152 B frag-major embeds
    __shared__ ushort4 WINTB[HIDDEN];         // 3072 B bf16 {w0,w1,w2,b}
    __shared__ float PF[64][7];               // 1792 B pos3,feat3,mval
    __shared__ float CNT[2];

    const int t  = threadIdx.x;
    const int bm = blockIdx.x;
    const int l = t & 63, ng = t >> 6, lg = l >> 4, l15 = l & 15;

    bf16x8 bA[6], bB[6];
    #define LOADB(dst, Wf, kt)                                                  \
        { const unsigned short* bp_ = &Wf[((size_t)((kt)*24 + ng*6)*64 + l)*8]; \
          _Pragma("unroll")                                                     \
          for (int nt_ = 0; nt_ < 6; ++nt_)                                     \
              dst[nt_] = *(const bf16x8*)(bp_ + (size_t)nt_*512); }
    #define AREAD(a_, kt)                                                       \
        { _Pragma("unroll")                                                     \
          for (int mt_ = 0; mt_ < 4; ++mt_)                                     \
              a_[mt_] = *(const bf16x8*)&G[(size_t)(((mt_*12 + (kt))*64) + l)*8]; }
    #define MFMA6(bfr, a_)                                                      \
        { __builtin_amdgcn_s_setprio(1);                                        \
          _Pragma("unroll")                                                     \
          for (int mt_ = 0; mt_ < 4; ++mt_)                                     \
              _Pragma("unroll")                                                 \
              for (int nt_ = 0; nt_ < 6; ++nt_)                                 \
                  acc[mt_][nt_] = __builtin_amdgcn_mfma_f32_16x16x32_bf16(      \
                      a_[mt_], bfr[nt_], acc[mt_][nt_], 0, 0, 0);               \
          __builtin_amdgcn_s_setprio(0); }

    if (t < 64) {
        const int e  = bm*64 + t;
        const int pi = nbr_idx[e];
        PF[t][0]=pos[pi*3];  PF[t][1]=pos[pi*3+1];  PF[t][2]=pos[pi*3+2];
        PF[t][3]=feat[pi*3]; PF[t][4]=feat[pi*3+1]; PF[t][5]=feat[pi*3+2];
        const int fmt = *mask_fmt;
        const int mv  = fmt ? (int)((const unsigned char*)mask_raw)[e]
                            : ((const int*)mask_raw)[e];
        PF[t][6] = mv ? 1.0f : 0.0f;
    }
    for (int d = t; d < HIDDEN; d += 256) {
        ushort4 wv;
        wv.x = f2bf(W_in[d]); wv.y = f2bf(W_in[HIDDEN+d]);
        wv.z = f2bf(W_in[2*HIDDEN+d]); wv.w = f2bf(b_in[d]);
        WINTB[d] = wv;
    }
    float b1r[6];
    #pragma unroll
    for (int nt = 0; nt < 6; ++nt) b1r[nt] = b1[ng*96 + nt*16 + l15];
    __syncthreads();
    if (t < 2) {
        float c = 0.f;
        for (int s = 0; s < 32; ++s) c += PF[t*32+s][6];
        CNT[t] = c;   // read after the phase-A barrier
    }

    const int er = t >> 2, seg = t & 3;
    float frA[8], frB[8];
    #pragma unroll
    for (int i = 0; i < 8; ++i) {
        frA[i] = exp2f(-(float)(seg*8 + i)      * 0.2076205059304601f);
        frB[i] = exp2f(-(float)(32 + seg*8 + i) * 0.2076205059304601f);
    }
    const float f0 = PF[er][3], f1 = PF[er][4], f2 = PF[er][5];
    const float pc0 = PF[er][0], pc1 = PF[er][1], pc2 = PF[er][2];
    const int slotbase = (er>>4)*12*64 + seg*16 + (er&15);

    #define EMB(kt_)                                                            \
        { const float pc = ((kt_)>>2)==0 ? pc0 : (((kt_)>>2)==1 ? pc1 : pc2);   \
          float v[8];                                                           \
          _Pragma("unroll")                                                     \
          for (int i = 0; i < 8; ++i) {                                         \
              const float fr = ((kt_)&1) ? frB[i] : frA[i];                     \
              const float aa = pc * fr;                                         \
              const float base = (((kt_)>>1)&1) ? __cosf(aa) : __sinf(aa);      \
              const ushort4 wv = WINTB[(kt_)*32 + seg*8 + i];                   \
              v[i] = fmaf(f0, b2f(wv.x), fmaf(f1, b2f(wv.y),                    \
                     fmaf(f2, b2f(wv.z), base + b2f(wv.w))));                   \
          }                                                                     \
          *(bf16x8*)&G[(size_t)(slotbase + (kt_)*64)*8] = pack8(v); }

    f32x4 acc[4][6];
    #pragma unroll
    for (int mt=0; mt<4; ++mt)
        #pragma unroll
        for (int nt=0; nt<6; ++nt) acc[mt][nt] = (f32x4){0.f,0.f,0.f,0.f};

    // ---- phase A: dst-half GEMM (snxb broadcast A) interleaved with embed ----
    const unsigned short* snx0 = &snxb[(size_t)(bm*2 + 0)*HIDDEN];
    const unsigned short* snx1 = &snxb[(size_t)(bm*2 + 1)*HIDDEN];
    #pragma unroll
    for (int kt = 0; kt < 12; ++kt) {
        LOADB(bA, W1df, kt);
        bf16x8 s0 = *(const bf16x8*)&snx0[kt*32 + lg*8];
        bf16x8 s1 = *(const bf16x8*)&snx1[kt*32 + lg*8];
        EMB(kt);
        __builtin_amdgcn_s_setprio(1);
        #pragma unroll
        for (int nt = 0; nt < 6; ++nt) {
            acc[0][nt] = __builtin_amdgcn_mfma_f32_16x16x32_bf16(s0, bA[nt], acc[0][nt], 0,0,0);
            acc[1][nt] = __builtin_amdgcn_mfma_f32_16x16x32_bf16(s0, bA[nt], acc[1][nt], 0,0,0);
            acc[2][nt] = __builtin_amdgcn_mfma_f32_16x16x32_bf16(s1, bA[nt], acc[2][nt], 0,0,0);
            acc[3][nt] = __builtin_amdgcn_mfma_f32_16x16x32_bf16(s1, bA[nt], acc[3][nt], 0,0,0);
        }
        __builtin_amdgcn_s_setprio(0);
    }
    __syncthreads();   // G complete (also orders CNT)

    // ---- phase B: src-half GEMM from LDS, B 2-deep prefetch ----
    LOADB(bA, W1sf, 0); LOADB(bB, W1sf, 1);
    #pragma unroll
    for (int kt = 0; kt < 12; kt += 2) {
        bf16x8 a[4];
        AREAD(a, kt);
        MFMA6(bA, a);
        if (kt + 2 < 12) LOADB(bA, W1sf, kt + 2);
        AREAD(a, kt + 1);
        MFMA6(bB, a);
        if (kt + 3 < 12) LOADB(bB, W1sf, kt + 3);
    }

    // ---- gelu + masked mean -> aggpre ----
    float mvr[4][4];
    #pragma unroll
    for (int mt=0; mt<4; ++mt)
        #pragma unroll
        for (int r=0; r<4; ++r)
            mvr[mt][r] = PF[mt*16 + lg*4 + r][6];
    #pragma unroll
    for (int nt=0; nt<6; ++nt) {
        const int col = ng*96 + nt*16 + l15;
        const float bb1 = b1r[nt];
        float s0 = 0.f, s1 = 0.f;
        #pragma unroll
        for (int mt=0; mt<4; ++mt) {
            float p = 0.f;
            #pragma unroll
            for (int r=0; r<4; ++r)
                p += mvr[mt][r] * gelu(acc[mt][nt][r] + bb1);
            if (mt < 2) s0 += p; else s1 += p;
        }
        s0 += __shfl_xor(s0,16); s0 += __shfl_xor(s0,32);
        s1 += __shfl_xor(s1,16); s1 += __shfl_xor(s1,32);
        if (lg == 0) {
            const int sn0 = bm*2;
            aggpre[(size_t)sn0*HIDDEN + col]     = f2bf(s0 / fmaxf(CNT[0],1.f));
            aggpre[(size_t)(sn0+1)*HIDDEN + col] = f2bf(s1 / fmaxf(CNT[1],1.f));
        }
    }
    if (t < 2) cntf[bm*2 + t] = CNT[t];
    #undef LOADB
    #undef AREAD
    #undef MFMA6
    #undef EMB
}

// ---- K3: aggb = aggpre @ W2 + b2*(cnt>0). 128 blocks = 32 rg x 4 cq ----
__global__ __launch_bounds__(256)
void k_agg(const unsigned short* __restrict__ aggpre,
           const unsigned short* __restrict__ w2f,
           const float* __restrict__ b2, const float* __restrict__ cntf,
           unsigned short* __restrict__ aggb) {
    const int rg = blockIdx.x >> 2, cq = blockIdx.x & 3;
    const int t = threadIdx.x, w = t>>6, l = t&63, lg = l>>4, l15 = l&15;
    const int wgm = w>>1, wgn = w&1;
    const int r0 = rg*64 + wgm*32;
    const int ntb = cq*6 + wgn*3;
    f32x4 acc[2][3];
    #pragma unroll
    for (int mt=0; mt<2; ++mt)
        #pragma unroll
        for (int nt=0; nt<3; ++nt) acc[mt][nt] = (f32x4){0.f,0.f,0.f,0.f};
    #pragma unroll 2
    for (int kt = 0; kt < 12; ++kt) {
        bf16x8 a[2], bfr[3];
        const unsigned short* bpp = &w2f[((size_t)(kt*24 + ntb)*64 + l)*8];
        #pragma unroll
        for (int nt=0; nt<3; ++nt) bfr[nt] = *(const bf16x8*)(bpp + (size_t)nt*512);
        #pragma unroll
        for (int mt=0; mt<2; ++mt)
            a[mt] = *(const bf16x8*)&aggpre[(size_t)(r0 + mt*16 + l15)*HIDDEN + kt*32 + lg*8];
        #pragma unroll
        for (int mt=0; mt<2; ++mt)
            #pragma unroll
            for (int nt=0; nt<3; ++nt)
                acc[mt][nt] = __builtin_amdgcn_mfma_f32_16x16x32_bf16(a[mt], bfr[nt], acc[mt][nt], 0,0,0);
    }
    #pragma unroll
    for (int mt=0; mt<2; ++mt)
        #pragma unroll
        for (int nt=0; nt<3; ++nt) {
            const int col = cq*96 + wgn*48 + nt*16 + l15;
            const float bb = b2[col];
            #pragma unroll
            for (int r=0; r<4; ++r) {
                const int row = r0 + mt*16 + lg*4 + r;
                const float nz = (cntf[row] > 0.f) ? 1.f : 0.f;
                aggb[(size_t)row*HIDDEN + col] = f2bf(acc[mt][nt][r] + bb*nz);
            }
        }
}

// ---- K4: projection out = [aggb|snxb] @ Wp + bp. 128 blocks = 32 rg x 4 cq ----
__global__ __launch_bounds__(256)
void k_proj(const unsigned short* __restrict__ aggb,
            const unsigned short* __restrict__ snxb,
            const unsigned short* __restrict__ wpf,
            const float* __restrict__ bp, float* __restrict__ out) {
    const int rg = blockIdx.x >> 2, cq = blockIdx.x & 3;
    const int t = threadIdx.x, w = t>>6, l = t&63, lg = l>>4, l15 = l&15;
    const int wgm = w>>1, wgn = w&1;
    const int r0 = rg*64 + wgm*32;
    const int ntb = cq*6 + wgn*3;
    f32x4 acc[2][3];
    #pragma unroll
    for (int mt=0; mt<2; ++mt)
        #pragma unroll
        for (int nt=0; nt<3; ++nt) acc[mt][nt] = (f32x4){0.f,0.f,0.f,0.f};
    #pragma unroll 2
    for (int kt = 0; kt < 24; ++kt) {
        const unsigned short* Ab = (kt < 12) ? aggb : snxb;
        const unsigned short* Wb = (kt < 12) ? wpf  : wpf + WBLK;
        const int ktt = (kt < 12) ? kt : kt - 12;
        bf16x8 a[2], bfr[3];
        const unsigned short* bpp = &Wb[((size_t)(ktt*24 + ntb)*64 + l)*8];
        #pragma unroll
        for (int nt=0; nt<3; ++nt) bfr[nt] = *(const bf16x8*)(bpp + (size_t)nt*512);
        #pragma unroll
        for (int mt=0; mt<2; ++mt)
            a[mt] = *(const bf16x8*)&Ab[(size_t)(r0 + mt*16 + l15)*HIDDEN + ktt*32 + lg*8];
        #pragma unroll
        for (int mt=0; mt<2; ++mt)
            #pragma unroll
            for (int nt=0; nt<3; ++nt)
                acc[mt][nt] = __builtin_amdgcn_mfma_f32_16x16x32_bf16(a[mt], bfr[nt], acc[mt][nt], 0,0,0);
    }
    #pragma unroll
    for (int mt=0; mt<2; ++mt)
        #pragma unroll
        for (int nt=0; nt<3; ++nt) {
            const int col = cq*96 + wgn*48 + nt*16 + l15;
            #pragma unroll
            for (int r=0; r<4; ++r) {
                const int row = r0 + mt*16 + lg*4 + r;
                out[(size_t)row*HIDDEN + col] = acc[mt][nt][r] + bp[col];
            }
        }
}

extern "C" void kernel_launch(void* const* d_in, const int* in_sizes, int n_in,
                              void* d_out, int out_size, void* d_ws, size_t ws_size,
                              hipStream_t stream) {
    const float* pos   = (const float*)d_in[0];
    const float* feat  = (const float*)d_in[1];
    const int*   sn    = (const int*)d_in[2];
    const int*   nbr   = (const int*)d_in[3];
    const void*  mask  = d_in[4];
    const float* W_in  = (const float*)d_in[5];
    const float* b_in  = (const float*)d_in[6];
    const float* W1    = (const float*)d_in[7];
    const float* b1    = (const float*)d_in[8];
    const float* W2    = (const float*)d_in[9];
    const float* b2    = (const float*)d_in[10];
    const float* Wp    = (const float*)d_in[11];
    const float* bpv   = (const float*)d_in[12];
    float* out = (float*)d_out;

    char* base = (char*)d_ws;
    int* flag = (int*)base;
    unsigned short* w1sf = (unsigned short*)(base + 256);
    unsigned short* w1df = w1sf + WBLK;
    unsigned short* w2f  = w1df + WBLK;
    unsigned short* wpf  = w2f  + WBLK;                  // 2 blocks (768 rows)
    unsigned short* snxb = wpf  + 2*(size_t)WBLK;        // 2048*384 bf16
    unsigned short* aggb = snxb + (size_t)NSUPER*HIDDEN;
    unsigned short* aggp = aggb + (size_t)NSUPER*HIDDEN; // 2048*384 bf16
    float* cntf = (float*)(aggp + (size_t)NSUPER*HIDDEN); // 2048 f32

    hipLaunchKernelGGL(prep, dim3(393), dim3(256), 0, stream,
                       W1, W2, Wp, (const unsigned int*)mask,
                       pos, feat, sn, W_in, b_in,
                       w1sf, w1df, w2f, wpf, snxb, flag);
    hipLaunchKernelGGL(k_mlp, dim3(1024), dim3(256), 0, stream,
                       pos, feat, nbr, mask, flag, W_in, b_in,
                       snxb, w1sf, w1df, b1, aggp, cntf);
    hipLaunchKernelGGL(k_agg, dim3(128), dim3(256), 0, stream,
                       aggp, w2f, b2, cntf, aggb);
    hipLaunchKernelGGL(k_proj, dim3(128), dim3(256), 0, stream,
                       aggb, snxb, wpf, bpv, out);
}